// Round 15
// baseline (581.970 us; speedup 1.0000x reference)
//
#include <hip/hip_runtime.h>
#include <hip/hip_bf16.h>

#define DMODEL 512
#define NHEADS 8
#define DFF 2048
#define NSEQ 2048
#define NROWS 4096

typedef __attribute__((ext_vector_type(8))) short   bf16x8;   // MFMA A/B frag
typedef __attribute__((ext_vector_type(4))) float   f32x4;    // MFMA C/D frag
typedef __attribute__((ext_vector_type(8))) unsigned short u16x8;

__device__ __forceinline__ unsigned short f2bf(float f) {
  union { float f; unsigned u; } v; v.f = f;
  unsigned r = v.u + 0x7fffu + ((v.u >> 16) & 1u);   // RNE
  return (unsigned short)(r >> 16);
}
__device__ __forceinline__ float bf2f(unsigned short u) {
  union { unsigned u; float f; } v; v.u = (unsigned)u << 16;
  return v.f;
}

#define GLL16(src, dst) \
  __builtin_amdgcn_global_load_lds((__attribute__((address_space(1))) const void*)(src), \
                                   (__attribute__((address_space(3))) void*)(dst), 16, 0, 0)

// ===========================================================================
// DIAGNOSTIC ROUND: idempotent kernels repeat REPS times internally so their
// true per-dispatch duration (dur/REPS) rises above the 44us harness fills
// and becomes visible in the top-5. Functional output is unchanged.
// ===========================================================================

// ---------------------------------------------------------------------------
// prep (REPS-diagnostic)
// ---------------------------------------------------------------------------
template<int REPS>
__global__ __launch_bounds__(256)
void prep(const float* __restrict__ w_qkv, const float* __restrict__ w_out,
          const float* __restrict__ w_ff1, const float* __restrict__ w_ff2,
          const float* __restrict__ ln1_g, const float* __restrict__ ln1_b,
          const float* __restrict__ ln2_g, const float* __restrict__ ln2_b,
          const float* __restrict__ b_qkv, const float* __restrict__ b_ff1,
          const float* __restrict__ x,
          unsigned short* __restrict__ wqkvT, unsigned short* __restrict__ woutT,
          unsigned short* __restrict__ wff1T, unsigned short* __restrict__ wff2T,
          float* __restrict__ vq, float* __restrict__ uq,
          float* __restrict__ vf, float* __restrict__ uf,
          unsigned short* __restrict__ x_bf, float2* __restrict__ stats1,
          float* __restrict__ stats2) {
  __shared__ char smem_raw[12288];
  const int tid = threadIdx.x;
  #pragma unroll 1
  for (int rep = 0; rep < REPS; ++rep) {
  __syncthreads();
  int bid = blockIdx.x;
  if (bid < 3072) {
    unsigned short (*t)[33] = (unsigned short (*)[33])smem_raw;
    const float* w; unsigned short* wT; const float* g; int K, N;
    if (bid < 768)       { w = w_qkv; wT = wqkvT; g = ln1_g; K = 512;  N = 1536; }
    else if (bid < 1024) { bid -= 768;  w = w_out; wT = woutT; g = nullptr; K = 512;  N = 512; }
    else if (bid < 2048) { bid -= 1024; w = w_ff1; wT = wff1T; g = ln2_g; K = 512;  N = 2048; }
    else                 { bid -= 2048; w = w_ff2; wT = wff2T; g = nullptr; K = 2048; N = 512; }
    const int ntx = N >> 5;
    const int n0 = (bid % ntx) * 32, k0 = (bid / ntx) * 32;
    const int tx = tid & 31, ty = tid >> 5;
    #pragma unroll
    for (int i = 0; i < 4; ++i) {
      const int k = k0 + ty + i * 8;
      const float s = g ? g[k] : 1.0f;
      t[ty + i * 8][tx] = f2bf(s * w[(size_t)k * N + n0 + tx]);
    }
    __syncthreads();
    #pragma unroll
    for (int i = 0; i < 4; ++i)
      wT[(size_t)(n0 + ty + i * 8) * K + k0 + tx] = t[tx][ty + i * 8];
  } else if (bid < 3100) {
    const int b = bid - 3072;
    const float *w, *g, *bb, *bias; float *ov, *ou; int N, n0;
    if (b < 12) { w = w_qkv; g = ln1_g; bb = ln1_b; bias = b_qkv;
                  ov = vq; ou = uq; N = 1536; n0 = b * 128; }
    else        { w = w_ff1; g = ln2_g; bb = ln2_b; bias = b_ff1;
                  ov = vf; ou = uf; N = 2048; n0 = (b - 12) * 128; }
    float*  sg = (float*)smem_raw;
    float*  sb = sg + 512;
    float4* pu = (float4*)(sb + 512);
    float4* pv = pu + 256;
    sg[tid] = g[tid];  sg[tid + 256] = g[tid + 256];
    sb[tid] = bb[tid]; sb[tid + 256] = bb[tid + 256];
    __syncthreads();
    const int c4 = tid & 31, kg = tid >> 5;
    float4 su = make_float4(0, 0, 0, 0), sv = make_float4(0, 0, 0, 0);
    const float* wp = w + (size_t)(kg * 64) * N + n0 + c4 * 4;
    #pragma unroll 8
    for (int kk = 0; kk < 64; ++kk) {
      const float4 wv = *(const float4*)(wp + (size_t)kk * N);
      const float gk = sg[kg * 64 + kk], bk = sb[kg * 64 + kk];
      su.x = fmaf(bk, wv.x, su.x); su.y = fmaf(bk, wv.y, su.y);
      su.z = fmaf(bk, wv.z, su.z); su.w = fmaf(bk, wv.w, su.w);
      sv.x = fmaf(gk, wv.x, sv.x); sv.y = fmaf(gk, wv.y, sv.y);
      sv.z = fmaf(gk, wv.z, sv.z); sv.w = fmaf(gk, wv.w, sv.w);
    }
    pu[kg * 32 + c4] = su; pv[kg * 32 + c4] = sv;
    __syncthreads();
    if (tid < 32) {
      float4 u = pu[tid], v = pv[tid];
      #pragma unroll
      for (int q = 1; q < 8; ++q) {
        const float4 a = pu[q * 32 + tid], c = pv[q * 32 + tid];
        u.x += a.x; u.y += a.y; u.z += a.z; u.w += a.w;
        v.x += c.x; v.y += c.y; v.z += c.z; v.w += c.w;
      }
      const float4 bv = *(const float4*)(bias + n0 + tid * 4);
      u.x += bv.x; u.y += bv.y; u.z += bv.z; u.w += bv.w;
      *(float4*)(ov + n0 + tid * 4) = v;
      *(float4*)(ou + n0 + tid * 4) = u;
    }
  } else if (bid < 4124) {
    const int row = (bid - 3100) * 4 + (tid >> 6);
    const int lane = tid & 63;
    const float* xr = x + (size_t)row * DMODEL + lane * 8;
    const float4 v0 = *(const float4*)(xr);
    const float4 v1 = *(const float4*)(xr + 4);
    float s  = v0.x + v0.y + v0.z + v0.w + v1.x + v1.y + v1.z + v1.w;
    float s2 = v0.x*v0.x + v0.y*v0.y + v0.z*v0.z + v0.w*v0.w
             + v1.x*v1.x + v1.y*v1.y + v1.z*v1.z + v1.w*v1.w;
    #pragma unroll
    for (int m = 1; m < 64; m <<= 1) {
      s  += __shfl_xor(s,  m);
      s2 += __shfl_xor(s2, m);
    }
    const float mu  = s * (1.0f / DMODEL);
    const float var = s2 * (1.0f / DMODEL) - mu * mu;
    const float rs  = rsqrtf(var + 1e-5f);
    if (lane == 0) stats1[row] = make_float2(mu, rs);
    u16x8 o;
    o[0] = f2bf(v0.x); o[1] = f2bf(v0.y); o[2] = f2bf(v0.z); o[3] = f2bf(v0.w);
    o[4] = f2bf(v1.x); o[5] = f2bf(v1.y); o[6] = f2bf(v1.z); o[7] = f2bf(v1.w);
    *(u16x8*)(x_bf + (size_t)row * DMODEL + lane * 8) = o;
  } else {
    const int idx = (bid - 4124) * 256 + tid;
    if (idx < 2 * NROWS) stats2[idx] = 0.0f;
  }
  }  // rep
}

// ---------------------------------------------------------------------------
// gemm128 BK=32 (round-14 version), REPS-diagnostic.
// ---------------------------------------------------------------------------
template<int MODE, int REPS>
__global__ __launch_bounds__(256, 3)
void gemm128(const unsigned short* __restrict__ A,
             const unsigned short* __restrict__ Bt,
             const float* __restrict__ v, const float* __restrict__ u,
             const float* __restrict__ stats, unsigned short* __restrict__ Cb,
             int M, int N, int LDA, int KL) {
  __shared__ unsigned short smem[24576];

  const int tid = threadIdx.x;
  const int w = tid >> 6, l = tid & 63;
  const int gx = N >> 7;
  const int nxy = gx * (M >> 7);
  int lin = blockIdx.x;
  lin = (lin & 7) * (nxy >> 3) + (lin >> 3);
  const int bn = (lin % gx) << 7;
  const int bm = (lin / gx) << 7;
  const int wr = (w >> 1) * 64;
  const int wc = (w & 1) * 64;
  const int lr = l & 15, kg = l >> 4;

  auto stage = [&](int buf, int k0) {
    unsigned short* As = smem + buf * 4096;
    unsigned short* Bs = smem + 12288 + buf * 4096;
    #pragma unroll
    for (int i = 0; i < 2; ++i) {
      const int g = i * 4 + w;
      const int c = g * 64 + l;
      const int row = c >> 2;
      const int kc = (c & 3) ^ (row & 3);
      GLL16(A + (size_t)(bm + row) * LDA + k0 + kc * 8, As + g * 512);
    }
    #pragma unroll
    for (int i = 0; i < 2; ++i) {
      const int g = i * 4 + w;
      const int c = g * 64 + l;
      const int row = c >> 2;
      const int kc = (c & 3) ^ (row & 3);
      GLL16(Bt + (size_t)(bn + row) * LDA + k0 + kc * 8, Bs + g * 512);
    }
  };

  #pragma unroll 1
  for (int rep = 0; rep < REPS; ++rep) {
  __syncthreads();
  f32x4 acc[4][4] = {};
  const int nt = KL >> 5;
  stage(0, 0);
  stage(1, 32);
  for (int t = 0; t < nt; ++t) {
    if (t + 1 < nt) {
      asm volatile("s_waitcnt vmcnt(4)" ::: "memory");
    } else {
      asm volatile("s_waitcnt vmcnt(0)" ::: "memory");
    }
    __builtin_amdgcn_sched_barrier(0);
    __builtin_amdgcn_s_barrier();
    __builtin_amdgcn_sched_barrier(0);
    if (t + 2 < nt) stage((t + 2) % 3, (t + 2) << 5);
    const unsigned short* As = smem + (t % 3) * 4096;
    const unsigned short* Bs = smem + 12288 + (t % 3) * 4096;
    bf16x8 af[4], bfv[4];
    #pragma unroll
    for (int mi = 0; mi < 4; ++mi) {
      const int row = wr + mi * 16 + lr;
      af[mi] = *(const bf16x8*)&As[(row * 4 + (kg ^ (row & 3))) * 8];
    }
    #pragma unroll
    for (int ni = 0; ni < 4; ++ni) {
      const int row = wc + ni * 16 + lr;
      bfv[ni] = *(const bf16x8*)&Bs[(row * 4 + (kg ^ (row & 3))) * 8];
    }
    __builtin_amdgcn_s_setprio(1);
    #pragma unroll
    for (int mi = 0; mi < 4; ++mi)
      #pragma unroll
      for (int ni = 0; ni < 4; ++ni)
        acc[mi][ni] = __builtin_amdgcn_mfma_f32_16x16x32_bf16(
            af[mi], bfv[ni], acc[mi][ni], 0, 0, 0);
    __builtin_amdgcn_s_setprio(0);
  }

  __syncthreads();
  float* sc = ((float*)smem) + w * (64 * 36);
  const int r2 = l >> 2, ch = l & 3, c0 = ch * 8;
  #pragma unroll
  for (int p = 0; p < 2; ++p) {
    #pragma unroll
    for (int mi = 0; mi < 4; ++mi)
      #pragma unroll
      for (int ni = 0; ni < 2; ++ni)
        #pragma unroll
        for (int reg = 0; reg < 4; ++reg)
          sc[(mi * 16 + kg * 4 + reg) * 36 + ni * 16 + lr] = acc[mi][p * 2 + ni][reg];
    #pragma unroll
    for (int i2 = 0; i2 < 4; ++i2) {
      const int rl = i2 * 16 + r2;
      const int grow = bm + wr + rl;
      const int gcol = bn + wc + p * 32 + c0;
      const float4 va = *(const float4*)&sc[rl * 36 + c0];
      const float4 vb = *(const float4*)&sc[rl * 36 + c0 + 4];
      float vals[8] = {va.x, va.y, va.z, va.w, vb.x, vb.y, vb.z, vb.w};
      float mu, rs;
      if (MODE == 4) {
        const float2 st = ((const float2*)stats)[grow];
        mu = st.x; rs = st.y;
      } else {
        const float2 st = ((const float2*)stats)[grow];
        mu = st.x * (1.0f / DMODEL);
        rs = rsqrtf(st.y * (1.0f / DMODEL) - mu * mu + 1e-5f);
      }
      const float4 v0 = *(const float4*)&v[gcol];
      const float4 v1 = *(const float4*)&v[gcol + 4];
      const float4 u0 = *(const float4*)&u[gcol];
      const float4 u1 = *(const float4*)&u[gcol + 4];
      const float vv[8] = {v0.x, v0.y, v0.z, v0.w, v1.x, v1.y, v1.z, v1.w};
      const float uu[8] = {u0.x, u0.y, u0.z, u0.w, u1.x, u1.y, u1.z, u1.w};
      u16x8 o;
      #pragma unroll
      for (int e = 0; e < 8; ++e) {
        float t = rs * (vals[e] - mu * vv[e]) + uu[e];
        if (MODE == 6) t = 0.5f * t * (1.0f + erff(t * 0.70710678118654752f));
        o[e] = f2bf(t);
      }
      *(u16x8*)&Cb[(size_t)grow * N + gcol] = o;
    }
    if (p == 0) __builtin_amdgcn_s_barrier();
  }
  }  // rep
}

// ---------------------------------------------------------------------------
// gemm_bf16 BM x 64 (round-10 version), REPS-diagnostic (REPS=1 for MODE 5).
// ---------------------------------------------------------------------------
template<int MODE, int BM, int REPS>
__global__ __launch_bounds__(256)
void gemm_bf16(const unsigned short* __restrict__ A,
               const unsigned short* __restrict__ Bt,
               const float* __restrict__ bias,
               const float* __restrict__ resf, const unsigned short* __restrict__ resb,
               float* __restrict__ stats, void* __restrict__ Cout,
               int M, int N, int LDA, int KL) {
  constexpr int MR = BM / 32;
  constexpr int PS = BM / 32 + 2;
  constexpr int ROWS = BM / 2;
  __shared__ unsigned short As[3][BM * 64];
  __shared__ unsigned short Bs[3][64 * 64];

  const int tid = threadIdx.x;
  const int w = tid >> 6, l = tid & 63;
  const int gx = N >> 6;
  const int nxy = gx * (M / BM);
  int lin = blockIdx.x;
  lin = (lin & 7) * (nxy >> 3) + (lin >> 3);
  const int bn = (lin % gx) << 6;
  const int bm = (lin / gx) * BM;
  const int wr = (w >> 1) * (BM >> 1);
  const int wc = (w & 1) * 32;
  const int lr = l & 15, kg = l >> 4;

  auto stage = [&](int buf, int k0) {
    #pragma unroll
    for (int i = 0; i < BM / 32; ++i) {
      const int g = i * 4 + w;
      const int c = g * 64 + l;
      const int row = c >> 3;
      const int kc = (c & 7) ^ (row & 7);
      GLL16(A + (size_t)(bm + row) * LDA + k0 + kc * 8, &As[buf][g * 512]);
    }
    #pragma unroll
    for (int i = 0; i < 2; ++i) {
      const int g = i * 4 + w;
      const int c = g * 64 + l;
      const int row = c >> 3;
      const int kc = (c & 7) ^ (row & 7);
      GLL16(Bt + (size_t)(bn + row) * LDA + k0 + kc * 8, &Bs[buf][g * 512]);
    }
  };

  #pragma unroll 1
  for (int rep = 0; rep < REPS; ++rep) {
  __syncthreads();
  f32x4 acc[MR][2] = {};
  const int nt = KL >> 6;
  stage(0, 0);
  stage(1, 64);
  for (int t = 0; t < nt; ++t) {
    if (t + 1 < nt) {
      asm volatile("s_waitcnt vmcnt(%0)" :: "n"(PS) : "memory");
    } else {
      asm volatile("s_waitcnt vmcnt(0)" ::: "memory");
    }
    __builtin_amdgcn_sched_barrier(0);
    __builtin_amdgcn_s_barrier();
    __builtin_amdgcn_sched_barrier(0);
    if (t + 2 < nt) stage((t + 2) % 3, (t + 2) << 6);
    const int cur = t % 3;
    #pragma unroll
    for (int ks = 0; ks < 2; ++ks) {
      const int cc = ks * 4 + kg;
      bf16x8 af[MR], bfv[2];
      #pragma unroll
      for (int mi = 0; mi < MR; ++mi) {
        const int row = wr + mi * 16 + lr;
        af[mi] = *(const bf16x8*)&As[cur][(row * 8 + (cc ^ (row & 7))) * 8];
      }
      #pragma unroll
      for (int ni = 0; ni < 2; ++ni) {
        const int row = wc + ni * 16 + lr;
        bfv[ni] = *(const bf16x8*)&Bs[cur][(row * 8 + (cc ^ (row & 7))) * 8];
      }
      __builtin_amdgcn_s_setprio(1);
      #pragma unroll
      for (int mi = 0; mi < MR; ++mi)
        #pragma unroll
        for (int ni = 0; ni < 2; ++ni)
          acc[mi][ni] = __builtin_amdgcn_mfma_f32_16x16x32_bf16(
              af[mi], bfv[ni], acc[mi][ni], 0, 0, 0);
      __builtin_amdgcn_s_setprio(0);
    }
  }

  __syncthreads();
  float* sc = ((float*)&As[0][0]) + w * (ROWS * 36);
  #pragma unroll
  for (int mi = 0; mi < MR; ++mi)
    #pragma unroll
    for (int ni = 0; ni < 2; ++ni)
      #pragma unroll
      for (int reg = 0; reg < 4; ++reg)
        sc[(mi * 16 + kg * 4 + reg) * 36 + ni * 16 + lr] = acc[mi][ni][reg];

  float* Cf = (float*)Cout;
  unsigned short* Cb = (unsigned short*)Cout;
  const int r2 = l >> 2, ch = l & 3;
  #pragma unroll
  for (int i2 = 0; i2 < ROWS / 16; ++i2) {
    const int rl = i2 * 16 + r2;
    const int grow = bm + wr + rl;
    const int c0 = ch * 8;
    const int gcol = bn + wc + c0;
    const float4 va = *(const float4*)&sc[rl * 36 + c0];
    const float4 vb = *(const float4*)&sc[rl * 36 + c0 + 4];
    float vals[8] = {va.x, va.y, va.z, va.w, vb.x, vb.y, vb.z, vb.w};

    if (MODE == 5) {
      const float4 b0 = *(const float4*)&bias[gcol];
      const float4 b1 = *(const float4*)&bias[gcol + 4];
      const float4 r0 = *(const float4*)&resf[(size_t)grow * N + gcol];
      const float4 r1 = *(const float4*)&resf[(size_t)grow * N + gcol + 4];
      const float bb[8] = {b0.x, b0.y, b0.z, b0.w, b1.x, b1.y, b1.z, b1.w};
      const float rr[8] = {r0.x, r0.y, r0.z, r0.w, r1.x, r1.y, r1.z, r1.w};
      float rsum = 0.0f, rsq = 0.0f;
      u16x8 o;
      #pragma unroll
      for (int e = 0; e < 8; ++e) {
        const float t = vals[e] + bb[e] + rr[e];
        o[e] = f2bf(t);
        rsum += t; rsq = fmaf(t, t, rsq);
      }
      *(u16x8*)&Cb[(size_t)grow * N + gcol] = o;
      rsum += __shfl_xor(rsum, 1); rsq += __shfl_xor(rsq, 1);
      rsum += __shfl_xor(rsum, 2); rsq += __shfl_xor(rsq, 2);
      if (ch == 0) {
        atomicAdd(&stats[2 * grow],     rsum);
        atomicAdd(&stats[2 * grow + 1], rsq);
      }
    }

    if (MODE == 7) {
      const float4 b0 = *(const float4*)&bias[gcol];
      const float4 b1 = *(const float4*)&bias[gcol + 4];
      const u16x8 rb = *(const u16x8*)&resb[(size_t)grow * N + gcol];
      const float bb[8] = {b0.x, b0.y, b0.z, b0.w, b1.x, b1.y, b1.z, b1.w};
      #pragma unroll
      for (int e = 0; e < 8; ++e) vals[e] += bb[e] + bf2f(rb[e]);
      *(float4*)&Cf[(size_t)grow * N + gcol] =
          make_float4(vals[0], vals[1], vals[2], vals[3]);
      *(float4*)&Cf[(size_t)grow * N + gcol + 4] =
          make_float4(vals[4], vals[5], vals[6], vals[7]);
    }
  }
  }  // rep
}

// ---------------------------------------------------------------------------
// attn (REPS-diagnostic)
// ---------------------------------------------------------------------------
#define CAP 256
template<int REPS>
__global__ __launch_bounds__(64)
void attn_kernel(const unsigned short* __restrict__ qkv,
                 const int* __restrict__ pos, const int* __restrict__ lvl,
                 unsigned short* __restrict__ out) {
  const int bid = blockIdx.x;
  const int r = (bid & 7) * (NROWS / 8) + (bid >> 3);
  const int i = r & (NSEQ - 1);
  const int base = r - i;
  const int lane = threadIdx.x;

  __shared__ int   s_idx[CAP];
  __shared__ int   s_cnt;
  __shared__ float s_sc[NHEADS][CAP];
  __shared__ float s_inv[NHEADS];

  #pragma unroll 1
  for (int rep = 0; rep < REPS; ++rep) {
  __syncthreads();
  if (lane == 0) s_cnt = 0;
  __syncthreads();

  const int li = lvl[r];
  const int2 pq = *(const int2*)(pos + 2 * r);
  const int win = (li == 0) ? 512 : (li == 1 ? 64 : 16);
  const int jlo = max(i - win + 1, 0);
  const int jhi = min(i + win - 1, NSEQ - 1);

  for (int j = jlo + lane; j <= jhi; j += 64) {
    const int rj = base + j;
    bool m = (j == i);
    if (!m) {
      const int lj = lvl[rj];
      const int2 pj = *(const int2*)(pos + 2 * rj);
      const int d = abs(pq.x - pj.x) + abs(pq.y - pj.y);
      m = (lj == li) && (d <= 1);
    }
    if (m) {
      const int p = atomicAdd(&s_cnt, 1);
      if (p < CAP) s_idx[p] = j;
    }
  }
  __syncthreads();
  const int cnt = min(s_cnt, CAP);

  const u16x8 qv = *(const u16x8*)(qkv + (size_t)r * 1536 + lane * 8);
  float qf[8];
  #pragma unroll
  for (int e = 0; e < 8; ++e) qf[e] = bf2f(qv[e]);

  for (int jj = 0; jj < cnt; ++jj) {
    const int rj = base + s_idx[jj];
    const u16x8 kv = *(const u16x8*)(qkv + (size_t)rj * 1536 + 512 + lane * 8);
    float p = 0.0f;
    #pragma unroll
    for (int e = 0; e < 8; ++e) p = fmaf(qf[e], bf2f(kv[e]), p);
    p += __shfl_xor(p, 1);
    p += __shfl_xor(p, 2);
    p += __shfl_xor(p, 4);
    if ((lane & 7) == 0) s_sc[lane >> 3][jj] = p * 0.125f;
  }
  __syncthreads();

  if (lane < 8) {
    float mx = -1e30f;
    for (int jj = 0; jj < cnt; ++jj) mx = fmaxf(mx, s_sc[lane][jj]);
    float den = 0.0f;
    for (int jj = 0; jj < cnt; ++jj) {
      const float e = expf(s_sc[lane][jj] - mx);
      s_sc[lane][jj] = e;
      den += e;
    }
    s_inv[lane] = 1.0f / den;
  }
  __syncthreads();

  const int h = lane >> 3;
  float a[8] = {};
  for (int jj = 0; jj < cnt; ++jj) {
    const float pp = s_sc[h][jj];
    const u16x8 vv = *(const u16x8*)(qkv + (size_t)(base + s_idx[jj]) * 1536 + 1024 + lane * 8);
    #pragma unroll
    for (int e = 0; e < 8; ++e) a[e] = fmaf(pp, bf2f(vv[e]), a[e]);
  }
  const float inv = s_inv[h];
  u16x8 o;
  #pragma unroll
  for (int e = 0; e < 8; ++e) o[e] = f2bf(a[e] * inv);
  *(u16x8*)(out + (size_t)r * DMODEL + lane * 8) = o;
  }  // rep
}

// ---------------------------------------------------------------------------
extern "C" void kernel_launch(void* const* d_in, const int* in_sizes, int n_in,
                              void* d_out, int out_size, void* d_ws, size_t ws_size,
                              hipStream_t stream) {
  const float* x            = (const float*)d_in[0];
  const int*   coords_pos   = (const int*)d_in[1];
  const int*   coords_level = (const int*)d_in[2];
  const float* w_qkv        = (const float*)d_in[3];
  const float* b_qkv        = (const float*)d_in[4];
  const float* w_out        = (const float*)d_in[5];
  const float* b_out        = (const float*)d_in[6];
  const float* w_ff1        = (const float*)d_in[7];
  const float* b_ff1        = (const float*)d_in[8];
  const float* w_ff2        = (const float*)d_in[9];
  const float* b_ff2        = (const float*)d_in[10];
  const float* ln1_g        = (const float*)d_in[11];
  const float* ln1_b        = (const float*)d_in[12];
  const float* ln2_g        = (const float*)d_in[13];
  const float* ln2_b        = (const float*)d_in[14];
  float* out = (float*)d_out;

  // workspace layout (bytes)
  char* ws = (char*)d_ws;
  unsigned short* qkv_bf = (unsigned short*)(ws);
  unsigned short* h_bf   = (unsigned short*)(ws);
  unsigned short* x_bf   = (unsigned short*)(ws + 16777216);
  unsigned short* at_bf  = (unsigned short*)(ws + 20971520);
  unsigned short* x1_bf  = (unsigned short*)(ws + 25165824);
  unsigned short* wqkvT  = (unsigned short*)(ws + 29360128);
  unsigned short* woutT  = (unsigned short*)(ws + 30932992);
  unsigned short* wff1T  = (unsigned short*)(ws + 31457280);
  unsigned short* wff2T  = (unsigned short*)(ws + 33554432);
  float*          vq     = (float*)(ws + 35651584);
  float*          uq     = (float*)(ws + 35657728);
  float*          vf     = (float*)(ws + 35663872);
  float*          uf     = (float*)(ws + 35672064);
  float2*         stats1 = (float2*)(ws + 35680256);
  float*          stats2 = (float*)(ws + 35713024);

  // DIAGNOSTIC: REPS=10 on idempotent kernels (dur/10 = true per-kernel time)
  prep<10><<<4156, 256, 0, stream>>>(w_qkv, w_out, w_ff1, w_ff2,
                                     ln1_g, ln1_b, ln2_g, ln2_b, b_qkv, b_ff1, x,
                                     wqkvT, woutT, wff1T, wff2T,
                                     vq, uq, vf, uf, x_bf, stats1, stats2);

  gemm128<4, 10><<<(1536/128)*(NROWS/128), 256, 0, stream>>>(
      x_bf, wqkvT, vq, uq, (const float*)stats1, qkv_bf, NROWS, 1536, DMODEL, DMODEL);

  attn_kernel<10><<<NROWS, 64, 0, stream>>>(qkv_bf, coords_pos, coords_level, at_bf);

  gemm_bf16<5, 64, 1><<<(DMODEL/64)*(NROWS/64), 256, 0, stream>>>(
      at_bf, woutT, b_out, x, nullptr, stats2, x1_bf, NROWS, DMODEL, DMODEL, DMODEL);

  gemm128<6, 10><<<(DFF/128)*(NROWS/128), 256, 0, stream>>>(
      x1_bf, wff1T, vf, uf, stats2, h_bf, NROWS, DFF, DMODEL, DMODEL);

  gemm_bf16<7, 64, 10><<<(DMODEL/64)*(NROWS/64), 256, 0, stream>>>(
      h_bf, wff2T, b_ff2, nullptr, x1_bf, nullptr, out, NROWS, DMODEL, DFF, DFF);
}

// Round 16
// 92.454 us; speedup vs baseline: 6.2947x; 6.2947x over previous
//
#include <hip/hip_runtime.h>
#include <hip/hip_bf16.h>

#define DMODEL 512
#define NHEADS 8
#define DFF 2048
#define NSEQ 2048
#define NROWS 4096

typedef __attribute__((ext_vector_type(8))) short   bf16x8;   // MFMA A/B frag
typedef __attribute__((ext_vector_type(4))) float   f32x4;    // MFMA C/D frag
typedef __attribute__((ext_vector_type(8))) unsigned short u16x8;

__device__ __forceinline__ unsigned short f2bf(float f) {
  union { float f; unsigned u; } v; v.f = f;
  unsigned r = v.u + 0x7fffu + ((v.u >> 16) & 1u);   // RNE
  return (unsigned short)(r >> 16);
}
__device__ __forceinline__ float bf2f(unsigned short u) {
  union { unsigned u; float f; } v; v.u = (unsigned)u << 16;
  return v.f;
}

#define GLL16(src, dst) \
  __builtin_amdgcn_global_load_lds((__attribute__((address_space(1))) const void*)(src), \
                                   (__attribute__((address_space(3))) void*)(dst), 16, 0, 0)

// ---------------------------------------------------------------------------
// prep (round-14 version)
// ---------------------------------------------------------------------------
__global__ __launch_bounds__(256)
void prep(const float* __restrict__ w_qkv, const float* __restrict__ w_out,
          const float* __restrict__ w_ff1, const float* __restrict__ w_ff2,
          const float* __restrict__ ln1_g, const float* __restrict__ ln1_b,
          const float* __restrict__ ln2_g, const float* __restrict__ ln2_b,
          const float* __restrict__ b_qkv, const float* __restrict__ b_ff1,
          const float* __restrict__ x,
          unsigned short* __restrict__ wqkvT, unsigned short* __restrict__ woutT,
          unsigned short* __restrict__ wff1T, unsigned short* __restrict__ wff2T,
          float* __restrict__ vq, float* __restrict__ uq,
          float* __restrict__ vf, float* __restrict__ uf,
          unsigned short* __restrict__ x_bf, float2* __restrict__ stats1,
          float* __restrict__ stats2) {
  __shared__ char smem_raw[12288];
  int bid = blockIdx.x;
  const int tid = threadIdx.x;
  if (bid < 3072) {
    unsigned short (*t)[33] = (unsigned short (*)[33])smem_raw;
    const float* w; unsigned short* wT; const float* g; int K, N;
    if (bid < 768)       { w = w_qkv; wT = wqkvT; g = ln1_g; K = 512;  N = 1536; }
    else if (bid < 1024) { bid -= 768;  w = w_out; wT = woutT; g = nullptr; K = 512;  N = 512; }
    else if (bid < 2048) { bid -= 1024; w = w_ff1; wT = wff1T; g = ln2_g; K = 512;  N = 2048; }
    else                 { bid -= 2048; w = w_ff2; wT = wff2T; g = nullptr; K = 2048; N = 512; }
    const int ntx = N >> 5;
    const int n0 = (bid % ntx) * 32, k0 = (bid / ntx) * 32;
    const int tx = tid & 31, ty = tid >> 5;
    #pragma unroll
    for (int i = 0; i < 4; ++i) {
      const int k = k0 + ty + i * 8;
      const float s = g ? g[k] : 1.0f;
      t[ty + i * 8][tx] = f2bf(s * w[(size_t)k * N + n0 + tx]);
    }
    __syncthreads();
    #pragma unroll
    for (int i = 0; i < 4; ++i)
      wT[(size_t)(n0 + ty + i * 8) * K + k0 + tx] = t[tx][ty + i * 8];
  } else if (bid < 3100) {
    const int b = bid - 3072;
    const float *w, *g, *bb, *bias; float *ov, *ou; int N, n0;
    if (b < 12) { w = w_qkv; g = ln1_g; bb = ln1_b; bias = b_qkv;
                  ov = vq; ou = uq; N = 1536; n0 = b * 128; }
    else        { w = w_ff1; g = ln2_g; bb = ln2_b; bias = b_ff1;
                  ov = vf; ou = uf; N = 2048; n0 = (b - 12) * 128; }
    float*  sg = (float*)smem_raw;
    float*  sb = sg + 512;
    float4* pu = (float4*)(sb + 512);
    float4* pv = pu + 256;
    sg[tid] = g[tid];  sg[tid + 256] = g[tid + 256];
    sb[tid] = bb[tid]; sb[tid + 256] = bb[tid + 256];
    __syncthreads();
    const int c4 = tid & 31, kg = tid >> 5;
    float4 su = make_float4(0, 0, 0, 0), sv = make_float4(0, 0, 0, 0);
    const float* wp = w + (size_t)(kg * 64) * N + n0 + c4 * 4;
    #pragma unroll 8
    for (int kk = 0; kk < 64; ++kk) {
      const float4 wv = *(const float4*)(wp + (size_t)kk * N);
      const float gk = sg[kg * 64 + kk], bk = sb[kg * 64 + kk];
      su.x = fmaf(bk, wv.x, su.x); su.y = fmaf(bk, wv.y, su.y);
      su.z = fmaf(bk, wv.z, su.z); su.w = fmaf(bk, wv.w, su.w);
      sv.x = fmaf(gk, wv.x, sv.x); sv.y = fmaf(gk, wv.y, sv.y);
      sv.z = fmaf(gk, wv.z, sv.z); sv.w = fmaf(gk, wv.w, sv.w);
    }
    pu[kg * 32 + c4] = su; pv[kg * 32 + c4] = sv;
    __syncthreads();
    if (tid < 32) {
      float4 u = pu[tid], v = pv[tid];
      #pragma unroll
      for (int q = 1; q < 8; ++q) {
        const float4 a = pu[q * 32 + tid], c = pv[q * 32 + tid];
        u.x += a.x; u.y += a.y; u.z += a.z; u.w += a.w;
        v.x += c.x; v.y += c.y; v.z += c.z; v.w += c.w;
      }
      const float4 bv = *(const float4*)(bias + n0 + tid * 4);
      u.x += bv.x; u.y += bv.y; u.z += bv.z; u.w += bv.w;
      *(float4*)(ov + n0 + tid * 4) = v;
      *(float4*)(ou + n0 + tid * 4) = u;
    }
  } else if (bid < 4124) {
    const int row = (bid - 3100) * 4 + (tid >> 6);
    const int lane = tid & 63;
    const float* xr = x + (size_t)row * DMODEL + lane * 8;
    const float4 v0 = *(const float4*)(xr);
    const float4 v1 = *(const float4*)(xr + 4);
    float s  = v0.x + v0.y + v0.z + v0.w + v1.x + v1.y + v1.z + v1.w;
    float s2 = v0.x*v0.x + v0.y*v0.y + v0.z*v0.z + v0.w*v0.w
             + v1.x*v1.x + v1.y*v1.y + v1.z*v1.z + v1.w*v1.w;
    #pragma unroll
    for (int m = 1; m < 64; m <<= 1) {
      s  += __shfl_xor(s,  m);
      s2 += __shfl_xor(s2, m);
    }
    const float mu  = s * (1.0f / DMODEL);
    const float var = s2 * (1.0f / DMODEL) - mu * mu;
    const float rs  = rsqrtf(var + 1e-5f);
    if (lane == 0) stats1[row] = make_float2(mu, rs);
    u16x8 o;
    o[0] = f2bf(v0.x); o[1] = f2bf(v0.y); o[2] = f2bf(v0.z); o[3] = f2bf(v0.w);
    o[4] = f2bf(v1.x); o[5] = f2bf(v1.y); o[6] = f2bf(v1.z); o[7] = f2bf(v1.w);
    *(u16x8*)(x_bf + (size_t)row * DMODEL + lane * 8) = o;
  } else {
    const int idx = (bid - 4124) * 256 + tid;
    if (idx < 2 * NROWS) stats2[idx] = 0.0f;
  }
}

// ---------------------------------------------------------------------------
// gemm128 BK=32, 3-buffer counted-vmcnt (round-14 version).
//  MODE 4: LN fold (stats1 mu/rs) -> bf16             (LN1+QKV)
//  MODE 6: LN fold (stats2 sum/sumsq) + GELU -> bf16  (LN2+FF1)
// ---------------------------------------------------------------------------
template<int MODE>
__global__ __launch_bounds__(256, 3)
void gemm128(const unsigned short* __restrict__ A,
             const unsigned short* __restrict__ Bt,
             const float* __restrict__ v, const float* __restrict__ u,
             const float* __restrict__ stats, unsigned short* __restrict__ Cb,
             int M, int N, int LDA, int KL) {
  __shared__ unsigned short smem[24576];

  const int tid = threadIdx.x;
  const int w = tid >> 6, l = tid & 63;
  const int gx = N >> 7;
  const int nxy = gx * (M >> 7);
  int lin = blockIdx.x;
  lin = (lin & 7) * (nxy >> 3) + (lin >> 3);
  const int bn = (lin % gx) << 7;
  const int bm = (lin / gx) << 7;
  const int wr = (w >> 1) * 64;
  const int wc = (w & 1) * 64;
  const int lr = l & 15, kg = l >> 4;

  f32x4 acc[4][4] = {};

  auto stage = [&](int buf, int k0) {
    unsigned short* As = smem + buf * 4096;
    unsigned short* Bs = smem + 12288 + buf * 4096;
    #pragma unroll
    for (int i = 0; i < 2; ++i) {
      const int g = i * 4 + w;
      const int c = g * 64 + l;
      const int row = c >> 2;
      const int kc = (c & 3) ^ (row & 3);
      GLL16(A + (size_t)(bm + row) * LDA + k0 + kc * 8, As + g * 512);
    }
    #pragma unroll
    for (int i = 0; i < 2; ++i) {
      const int g = i * 4 + w;
      const int c = g * 64 + l;
      const int row = c >> 2;
      const int kc = (c & 3) ^ (row & 3);
      GLL16(Bt + (size_t)(bn + row) * LDA + k0 + kc * 8, Bs + g * 512);
    }
  };

  const int nt = KL >> 5;
  stage(0, 0);
  stage(1, 32);
  for (int t = 0; t < nt; ++t) {
    if (t + 1 < nt) {
      asm volatile("s_waitcnt vmcnt(4)" ::: "memory");
    } else {
      asm volatile("s_waitcnt vmcnt(0)" ::: "memory");
    }
    __builtin_amdgcn_sched_barrier(0);
    __builtin_amdgcn_s_barrier();
    __builtin_amdgcn_sched_barrier(0);
    if (t + 2 < nt) stage((t + 2) % 3, (t + 2) << 5);
    const unsigned short* As = smem + (t % 3) * 4096;
    const unsigned short* Bs = smem + 12288 + (t % 3) * 4096;
    bf16x8 af[4], bfv[4];
    #pragma unroll
    for (int mi = 0; mi < 4; ++mi) {
      const int row = wr + mi * 16 + lr;
      af[mi] = *(const bf16x8*)&As[(row * 4 + (kg ^ (row & 3))) * 8];
    }
    #pragma unroll
    for (int ni = 0; ni < 4; ++ni) {
      const int row = wc + ni * 16 + lr;
      bfv[ni] = *(const bf16x8*)&Bs[(row * 4 + (kg ^ (row & 3))) * 8];
    }
    __builtin_amdgcn_s_setprio(1);
    #pragma unroll
    for (int mi = 0; mi < 4; ++mi)
      #pragma unroll
      for (int ni = 0; ni < 4; ++ni)
        acc[mi][ni] = __builtin_amdgcn_mfma_f32_16x16x32_bf16(
            af[mi], bfv[ni], acc[mi][ni], 0, 0, 0);
    __builtin_amdgcn_s_setprio(0);
  }

  // ---- epilogue ----
  __syncthreads();
  float* sc = ((float*)smem) + w * (64 * 36);
  const int r2 = l >> 2, ch = l & 3, c0 = ch * 8;
  #pragma unroll
  for (int p = 0; p < 2; ++p) {
    #pragma unroll
    for (int mi = 0; mi < 4; ++mi)
      #pragma unroll
      for (int ni = 0; ni < 2; ++ni)
        #pragma unroll
        for (int reg = 0; reg < 4; ++reg)
          sc[(mi * 16 + kg * 4 + reg) * 36 + ni * 16 + lr] = acc[mi][p * 2 + ni][reg];
    #pragma unroll
    for (int i2 = 0; i2 < 4; ++i2) {
      const int rl = i2 * 16 + r2;
      const int grow = bm + wr + rl;
      const int gcol = bn + wc + p * 32 + c0;
      const float4 va = *(const float4*)&sc[rl * 36 + c0];
      const float4 vb = *(const float4*)&sc[rl * 36 + c0 + 4];
      float vals[8] = {va.x, va.y, va.z, va.w, vb.x, vb.y, vb.z, vb.w};
      float mu, rs;
      if (MODE == 4) {
        const float2 st = ((const float2*)stats)[grow];
        mu = st.x; rs = st.y;
      } else {
        const float2 st = ((const float2*)stats)[grow];
        mu = st.x * (1.0f / DMODEL);
        rs = rsqrtf(st.y * (1.0f / DMODEL) - mu * mu + 1e-5f);
      }
      const float4 v0 = *(const float4*)&v[gcol];
      const float4 v1 = *(const float4*)&v[gcol + 4];
      const float4 u0 = *(const float4*)&u[gcol];
      const float4 u1 = *(const float4*)&u[gcol + 4];
      const float vv[8] = {v0.x, v0.y, v0.z, v0.w, v1.x, v1.y, v1.z, v1.w};
      const float uu[8] = {u0.x, u0.y, u0.z, u0.w, u1.x, u1.y, u1.z, u1.w};
      u16x8 o;
      #pragma unroll
      for (int e = 0; e < 8; ++e) {
        float t = rs * (vals[e] - mu * vv[e]) + uu[e];
        if (MODE == 6) t = 0.5f * t * (1.0f + erff(t * 0.70710678118654752f));
        o[e] = f2bf(t);
      }
      *(u16x8*)&Cb[(size_t)grow * N + gcol] = o;
    }
    if (p == 0) __builtin_amdgcn_s_barrier();
  }
}

// ---------------------------------------------------------------------------
// BM x 64 bf16 MFMA GEMM, 5-buffer / 4-deep counted-vmcnt pipeline (N=512).
// Diagnostic showed FF2 latency-bound (MfmaUtil 15.7%, HBM 10%): 3-buffer
// lookahead (~400cy) < HBM latency (~900cy). 5 buffers = 80KB LDS; grid=512
// gives 2 blocks/CU regardless (LDS <= 80KB), so depth is free.
//  MODE 5: +bias +res(fp32) -> bf16, atomic row stats   (out-proj -> x1)
//  MODE 7: +bias +res(bf16) -> fp32                     (FF2 -> out)
// ---------------------------------------------------------------------------
template<int MODE, int BM>
__global__ __launch_bounds__(256)
void gemm_bf16(const unsigned short* __restrict__ A,
               const unsigned short* __restrict__ Bt,
               const float* __restrict__ bias,
               const float* __restrict__ resf, const unsigned short* __restrict__ resb,
               float* __restrict__ stats, void* __restrict__ Cout,
               int M, int N, int LDA, int KL) {
  constexpr int MR = BM / 32;
  constexpr int PS = BM / 32 + 2;             // GLLs per wave per stage (4)
  constexpr int ROWS = BM / 2;
  __shared__ unsigned short As[5][BM * 64];
  __shared__ unsigned short Bs[5][64 * 64];

  const int tid = threadIdx.x;
  const int w = tid >> 6, l = tid & 63;
  const int gx = N >> 6;
  const int nxy = gx * (M / BM);
  int lin = blockIdx.x;
  lin = (lin & 7) * (nxy >> 3) + (lin >> 3);
  const int bn = (lin % gx) << 6;
  const int bm = (lin / gx) * BM;
  const int wr = (w >> 1) * (BM >> 1);
  const int wc = (w & 1) * 32;
  const int lr = l & 15, kg = l >> 4;

  f32x4 acc[MR][2] = {};

  auto stage = [&](int buf, int k0) {
    #pragma unroll
    for (int i = 0; i < BM / 32; ++i) {
      const int g = i * 4 + w;
      const int c = g * 64 + l;
      const int row = c >> 3;
      const int kc = (c & 7) ^ (row & 7);
      GLL16(A + (size_t)(bm + row) * LDA + k0 + kc * 8, &As[buf][g * 512]);
    }
    #pragma unroll
    for (int i = 0; i < 2; ++i) {
      const int g = i * 4 + w;
      const int c = g * 64 + l;
      const int row = c >> 3;
      const int kc = (c & 7) ^ (row & 7);
      GLL16(Bt + (size_t)(bn + row) * LDA + k0 + kc * 8, &Bs[buf][g * 512]);
    }
  };

  const int nt = KL >> 6;                      // 8 (K=512) or 32 (K=2048)
  stage(0, 0);
  stage(1, 64);
  stage(2, 128);
  stage(3, 192);
  for (int t = 0; t < nt; ++t) {
    // tile t must be resident; tiles t+1..t+3 may stay in flight
    const int rem = nt - 1 - t;
    if (rem >= 3)      { asm volatile("s_waitcnt vmcnt(%0)" :: "n"(3 * PS) : "memory"); }
    else if (rem == 2) { asm volatile("s_waitcnt vmcnt(%0)" :: "n"(2 * PS) : "memory"); }
    else if (rem == 1) { asm volatile("s_waitcnt vmcnt(%0)" :: "n"(PS)     : "memory"); }
    else               { asm volatile("s_waitcnt vmcnt(0)" ::: "memory"); }
    __builtin_amdgcn_sched_barrier(0);
    __builtin_amdgcn_s_barrier();
    __builtin_amdgcn_sched_barrier(0);
    if (t + 4 < nt) stage((t + 4) % 5, (t + 4) << 6);
    const int cur = t % 5;
    #pragma unroll
    for (int ks = 0; ks < 2; ++ks) {
      const int cc = ks * 4 + kg;
      bf16x8 af[MR], bfv[2];
      #pragma unroll
      for (int mi = 0; mi < MR; ++mi) {
        const int row = wr + mi * 16 + lr;
        af[mi] = *(const bf16x8*)&As[cur][(row * 8 + (cc ^ (row & 7))) * 8];
      }
      #pragma unroll
      for (int ni = 0; ni < 2; ++ni) {
        const int row = wc + ni * 16 + lr;
        bfv[ni] = *(const bf16x8*)&Bs[cur][(row * 8 + (cc ^ (row & 7))) * 8];
      }
      __builtin_amdgcn_s_setprio(1);
      #pragma unroll
      for (int mi = 0; mi < MR; ++mi)
        #pragma unroll
        for (int ni = 0; ni < 2; ++ni)
          acc[mi][ni] = __builtin_amdgcn_mfma_f32_16x16x32_bf16(
              af[mi], bfv[ni], acc[mi][ni], 0, 0, 0);
      __builtin_amdgcn_s_setprio(0);
    }
  }

  // ---- epilogue: LDS transpose -> vectorized per-row processing ----
  __syncthreads();
  float* sc = ((float*)&As[0][0]) + w * (ROWS * 36);
  #pragma unroll
  for (int mi = 0; mi < MR; ++mi)
    #pragma unroll
    for (int ni = 0; ni < 2; ++ni)
      #pragma unroll
      for (int reg = 0; reg < 4; ++reg)
        sc[(mi * 16 + kg * 4 + reg) * 36 + ni * 16 + lr] = acc[mi][ni][reg];

  float* Cf = (float*)Cout;
  unsigned short* Cb = (unsigned short*)Cout;
  const int r2 = l >> 2, ch = l & 3;
  #pragma unroll
  for (int i2 = 0; i2 < ROWS / 16; ++i2) {
    const int rl = i2 * 16 + r2;
    const int grow = bm + wr + rl;
    const int c0 = ch * 8;
    const int gcol = bn + wc + c0;
    const float4 va = *(const float4*)&sc[rl * 36 + c0];
    const float4 vb = *(const float4*)&sc[rl * 36 + c0 + 4];
    float vals[8] = {va.x, va.y, va.z, va.w, vb.x, vb.y, vb.z, vb.w};

    if (MODE == 5) {
      const float4 b0 = *(const float4*)&bias[gcol];
      const float4 b1 = *(const float4*)&bias[gcol + 4];
      const float4 r0 = *(const float4*)&resf[(size_t)grow * N + gcol];
      const float4 r1 = *(const float4*)&resf[(size_t)grow * N + gcol + 4];
      const float bb[8] = {b0.x, b0.y, b0.z, b0.w, b1.x, b1.y, b1.z, b1.w};
      const float rr[8] = {r0.x, r0.y, r0.z, r0.w, r1.x, r1.y, r1.z, r1.w};
      float rsum = 0.0f, rsq = 0.0f;
      u16x8 o;
      #pragma unroll
      for (int e = 0; e < 8; ++e) {
        const float t = vals[e] + bb[e] + rr[e];
        o[e] = f2bf(t);
        rsum += t; rsq = fmaf(t, t, rsq);
      }
      *(u16x8*)&Cb[(size_t)grow * N + gcol] = o;
      rsum += __shfl_xor(rsum, 1); rsq += __shfl_xor(rsq, 1);
      rsum += __shfl_xor(rsum, 2); rsq += __shfl_xor(rsq, 2);
      if (ch == 0) {
        atomicAdd(&stats[2 * grow],     rsum);
        atomicAdd(&stats[2 * grow + 1], rsq);
      }
    }

    if (MODE == 7) {
      const float4 b0 = *(const float4*)&bias[gcol];
      const float4 b1 = *(const float4*)&bias[gcol + 4];
      const u16x8 rb = *(const u16x8*)&resb[(size_t)grow * N + gcol];
      const float bb[8] = {b0.x, b0.y, b0.z, b0.w, b1.x, b1.y, b1.z, b1.w};
      #pragma unroll
      for (int e = 0; e < 8; ++e) vals[e] += bb[e] + bf2f(rb[e]);
      *(float4*)&Cf[(size_t)grow * N + gcol] =
          make_float4(vals[0], vals[1], vals[2], vals[3]);
      *(float4*)&Cf[(size_t)grow * N + gcol + 4] =
          make_float4(vals[4], vals[5], vals[6], vals[7]);
    }
  }
}

// ---------------------------------------------------------------------------
// Sparse geometric attention (round-13 version).
// ---------------------------------------------------------------------------
#define CAP 256
__global__ __launch_bounds__(64)
void attn_kernel(const unsigned short* __restrict__ qkv,
                 const int* __restrict__ pos, const int* __restrict__ lvl,
                 unsigned short* __restrict__ out) {
  const int bid = blockIdx.x;
  const int r = (bid & 7) * (NROWS / 8) + (bid >> 3);
  const int i = r & (NSEQ - 1);
  const int base = r - i;
  const int lane = threadIdx.x;

  __shared__ int   s_idx[CAP];
  __shared__ int   s_cnt;
  __shared__ float s_sc[NHEADS][CAP];
  __shared__ float s_inv[NHEADS];

  if (lane == 0) s_cnt = 0;
  __syncthreads();

  const int li = lvl[r];
  const int2 pq = *(const int2*)(pos + 2 * r);
  const int win = (li == 0) ? 512 : (li == 1 ? 64 : 16);
  const int jlo = max(i - win + 1, 0);
  const int jhi = min(i + win - 1, NSEQ - 1);

  for (int j = jlo + lane; j <= jhi; j += 64) {
    const int rj = base + j;
    bool m = (j == i);
    if (!m) {
      const int lj = lvl[rj];
      const int2 pj = *(const int2*)(pos + 2 * rj);
      const int d = abs(pq.x - pj.x) + abs(pq.y - pj.y);
      m = (lj == li) && (d <= 1);
    }
    if (m) {
      const int p = atomicAdd(&s_cnt, 1);
      if (p < CAP) s_idx[p] = j;
    }
  }
  __syncthreads();
  const int cnt = min(s_cnt, CAP);

  const u16x8 qv = *(const u16x8*)(qkv + (size_t)r * 1536 + lane * 8);
  float qf[8];
  #pragma unroll
  for (int e = 0; e < 8; ++e) qf[e] = bf2f(qv[e]);

  for (int jj = 0; jj < cnt; ++jj) {
    const int rj = base + s_idx[jj];
    const u16x8 kv = *(const u16x8*)(qkv + (size_t)rj * 1536 + 512 + lane * 8);
    float p = 0.0f;
    #pragma unroll
    for (int e = 0; e < 8; ++e) p = fmaf(qf[e], bf2f(kv[e]), p);
    p += __shfl_xor(p, 1);
    p += __shfl_xor(p, 2);
    p += __shfl_xor(p, 4);
    if ((lane & 7) == 0) s_sc[lane >> 3][jj] = p * 0.125f;
  }
  __syncthreads();

  if (lane < 8) {
    float mx = -1e30f;
    for (int jj = 0; jj < cnt; ++jj) mx = fmaxf(mx, s_sc[lane][jj]);
    float den = 0.0f;
    for (int jj = 0; jj < cnt; ++jj) {
      const float e = expf(s_sc[lane][jj] - mx);
      s_sc[lane][jj] = e;
      den += e;
    }
    s_inv[lane] = 1.0f / den;
  }
  __syncthreads();

  const int h = lane >> 3;
  float a[8] = {};
  for (int jj = 0; jj < cnt; ++jj) {
    const float pp = s_sc[h][jj];
    const u16x8 vv = *(const u16x8*)(qkv + (size_t)(base + s_idx[jj]) * 1536 + 1024 + lane * 8);
    #pragma unroll
    for (int e = 0; e < 8; ++e) a[e] = fmaf(pp, bf2f(vv[e]), a[e]);
  }
  const float inv = s_inv[h];
  u16x8 o;
  #pragma unroll
  for (int e = 0; e < 8; ++e) o[e] = f2bf(a[e] * inv);
  *(u16x8*)(out + (size_t)r * DMODEL + lane * 8) = o;
}

// ---------------------------------------------------------------------------
extern "C" void kernel_launch(void* const* d_in, const int* in_sizes, int n_in,
                              void* d_out, int out_size, void* d_ws, size_t ws_size,
                              hipStream_t stream) {
  const float* x            = (const float*)d_in[0];
  const int*   coords_pos   = (const int*)d_in[1];
  const int*   coords_level = (const int*)d_in[2];
  const float* w_qkv        = (const float*)d_in[3];
  const float* b_qkv        = (const float*)d_in[4];
  const float* w_out        = (const float*)d_in[5];
  const float* b_out        = (const float*)d_in[6];
  const float* w_ff1        = (const float*)d_in[7];
  const float* b_ff1        = (const float*)d_in[8];
  const float* w_ff2        = (const float*)d_in[9];
  const float* b_ff2        = (const float*)d_in[10];
  const float* ln1_g        = (const float*)d_in[11];
  const float* ln1_b        = (const float*)d_in[12];
  const float* ln2_g        = (const float*)d_in[13];
  const float* ln2_b        = (const float*)d_in[14];
  float* out = (float*)d_out;

  // workspace layout (bytes)
  char* ws = (char*)d_ws;
  unsigned short* qkv_bf = (unsigned short*)(ws);
  unsigned short* h_bf   = (unsigned short*)(ws);
  unsigned short* x_bf   = (unsigned short*)(ws + 16777216);
  unsigned short* at_bf  = (unsigned short*)(ws + 20971520);
  unsigned short* x1_bf  = (unsigned short*)(ws + 25165824);
  unsigned short* wqkvT  = (unsigned short*)(ws + 29360128);
  unsigned short* woutT  = (unsigned short*)(ws + 30932992);
  unsigned short* wff1T  = (unsigned short*)(ws + 31457280);
  unsigned short* wff2T  = (unsigned short*)(ws + 33554432);
  float*          vq     = (float*)(ws + 35651584);
  float*          uq     = (float*)(ws + 35657728);
  float*          vf     = (float*)(ws + 35663872);
  float*          uf     = (float*)(ws + 35672064);
  float2*         stats1 = (float2*)(ws + 35680256);
  float*          stats2 = (float*)(ws + 35713024);

  // 1. prep
  prep<<<4156, 256, 0, stream>>>(w_qkv, w_out, w_ff1, w_ff2,
                                 ln1_g, ln1_b, ln2_g, ln2_b, b_qkv, b_ff1, x,
                                 wqkvT, woutT, wff1T, wff2T,
                                 vq, uq, vf, uf, x_bf, stats1, stats2);

  // 2. LN1+QKV fused -> bf16
  gemm128<4><<<(1536/128)*(NROWS/128), 256, 0, stream>>>(
      x_bf, wqkvT, vq, uq, (const float*)stats1, qkv_bf, NROWS, 1536, DMODEL, DMODEL);

  // 3. sparse geometric attention -> bf16
  attn_kernel<<<NROWS, 64, 0, stream>>>(qkv_bf, coords_pos, coords_level, at_bf);

  // 4. out-proj + residual(x fp32) -> x1 bf16, atomic row stats
  gemm_bf16<5, 64><<<(DMODEL/64)*(NROWS/64), 256, 0, stream>>>(
      at_bf, woutT, b_out, x, nullptr, stats2, x1_bf, NROWS, DMODEL, DMODEL, DMODEL);

  // 5. LN2+FF1+GELU fused -> bf16
  gemm128<6><<<(DFF/128)*(NROWS/128), 256, 0, stream>>>(
      x1_bf, wff1T, vf, uf, stats2, h_bf, NROWS, DFF, DMODEL, DMODEL);

  // 6. FF2 + residual(x1 bf16) -> d_out fp32  (5-buffer deep pipeline)
  gemm_bf16<7, 64><<<(DMODEL/64)*(NROWS/64), 256, 0, stream>>>(
      h_bf, wff2T, b_ff2, nullptr, x1_bf, nullptr, out, NROWS, DMODEL, DFF, DFF);
}

// Round 19
// 89.871 us; speedup vs baseline: 6.4756x; 1.0287x over previous
//
#include <hip/hip_runtime.h>
#include <hip/hip_bf16.h>

#define DMODEL 512
#define NHEADS 8
#define DFF 2048
#define NSEQ 2048
#define NROWS 4096

typedef __attribute__((ext_vector_type(8))) short   bf16x8;   // MFMA A/B frag
typedef __attribute__((ext_vector_type(4))) float   f32x4;    // MFMA C/D frag
typedef __attribute__((ext_vector_type(8))) unsigned short u16x8;

__device__ __forceinline__ unsigned short f2bf(float f) {
  union { float f; unsigned u; } v; v.f = f;
  unsigned r = v.u + 0x7fffu + ((v.u >> 16) & 1u);   // RNE
  return (unsigned short)(r >> 16);
}
__device__ __forceinline__ float bf2f(unsigned short u) {
  union { unsigned u; float f; } v; v.u = (unsigned)u << 16;
  return v.f;
}

#define GLL16(src, dst) \
  __builtin_amdgcn_global_load_lds((__attribute__((address_space(1))) const void*)(src), \
                                   (__attribute__((address_space(3))) void*)(dst), 16, 0, 0)

// ---------------------------------------------------------------------------
// prep: weight transposes (+gamma fold), u/v colsums, x stats + bf16 cast,
// stats2 zero. (round-14 version)
// ---------------------------------------------------------------------------
__global__ __launch_bounds__(256)
void prep(const float* __restrict__ w_qkv, const float* __restrict__ w_out,
          const float* __restrict__ w_ff1, const float* __restrict__ w_ff2,
          const float* __restrict__ ln1_g, const float* __restrict__ ln1_b,
          const float* __restrict__ ln2_g, const float* __restrict__ ln2_b,
          const float* __restrict__ b_qkv, const float* __restrict__ b_ff1,
          const float* __restrict__ x,
          unsigned short* __restrict__ wqkvT, unsigned short* __restrict__ woutT,
          unsigned short* __restrict__ wff1T, unsigned short* __restrict__ wff2T,
          float* __restrict__ vq, float* __restrict__ uq,
          float* __restrict__ vf, float* __restrict__ uf,
          unsigned short* __restrict__ x_bf, float2* __restrict__ stats1,
          float* __restrict__ stats2) {
  __shared__ char smem_raw[12288];
  int bid = blockIdx.x;
  const int tid = threadIdx.x;
  if (bid < 3072) {
    unsigned short (*t)[33] = (unsigned short (*)[33])smem_raw;
    const float* w; unsigned short* wT; const float* g; int K, N;
    if (bid < 768)       { w = w_qkv; wT = wqkvT; g = ln1_g; K = 512;  N = 1536; }
    else if (bid < 1024) { bid -= 768;  w = w_out; wT = woutT; g = nullptr; K = 512;  N = 512; }
    else if (bid < 2048) { bid -= 1024; w = w_ff1; wT = wff1T; g = ln2_g; K = 512;  N = 2048; }
    else                 { bid -= 2048; w = w_ff2; wT = wff2T; g = nullptr; K = 2048; N = 512; }
    const int ntx = N >> 5;
    const int n0 = (bid % ntx) * 32, k0 = (bid / ntx) * 32;
    const int tx = tid & 31, ty = tid >> 5;
    #pragma unroll
    for (int i = 0; i < 4; ++i) {
      const int k = k0 + ty + i * 8;
      const float s = g ? g[k] : 1.0f;
      t[ty + i * 8][tx] = f2bf(s * w[(size_t)k * N + n0 + tx]);
    }
    __syncthreads();
    #pragma unroll
    for (int i = 0; i < 4; ++i)
      wT[(size_t)(n0 + ty + i * 8) * K + k0 + tx] = t[tx][ty + i * 8];
  } else if (bid < 3100) {
    const int b = bid - 3072;
    const float *w, *g, *bb, *bias; float *ov, *ou; int N, n0;
    if (b < 12) { w = w_qkv; g = ln1_g; bb = ln1_b; bias = b_qkv;
                  ov = vq; ou = uq; N = 1536; n0 = b * 128; }
    else        { w = w_ff1; g = ln2_g; bb = ln2_b; bias = b_ff1;
                  ov = vf; ou = uf; N = 2048; n0 = (b - 12) * 128; }
    float*  sg = (float*)smem_raw;
    float*  sb = sg + 512;
    float4* pu = (float4*)(sb + 512);
    float4* pv = pu + 256;
    sg[tid] = g[tid];  sg[tid + 256] = g[tid + 256];
    sb[tid] = bb[tid]; sb[tid + 256] = bb[tid + 256];
    __syncthreads();
    const int c4 = tid & 31, kg = tid >> 5;
    float4 su = make_float4(0, 0, 0, 0), sv = make_float4(0, 0, 0, 0);
    const float* wp = w + (size_t)(kg * 64) * N + n0 + c4 * 4;
    #pragma unroll 8
    for (int kk = 0; kk < 64; ++kk) {
      const float4 wv = *(const float4*)(wp + (size_t)kk * N);
      const float gk = sg[kg * 64 + kk], bk = sb[kg * 64 + kk];
      su.x = fmaf(bk, wv.x, su.x); su.y = fmaf(bk, wv.y, su.y);
      su.z = fmaf(bk, wv.z, su.z); su.w = fmaf(bk, wv.w, su.w);
      sv.x = fmaf(gk, wv.x, sv.x); sv.y = fmaf(gk, wv.y, sv.y);
      sv.z = fmaf(gk, wv.z, sv.z); sv.w = fmaf(gk, wv.w, sv.w);
    }
    pu[kg * 32 + c4] = su; pv[kg * 32 + c4] = sv;
    __syncthreads();
    if (tid < 32) {
      float4 u = pu[tid], v = pv[tid];
      #pragma unroll
      for (int q = 1; q < 8; ++q) {
        const float4 a = pu[q * 32 + tid], c = pv[q * 32 + tid];
        u.x += a.x; u.y += a.y; u.z += a.z; u.w += a.w;
        v.x += c.x; v.y += c.y; v.z += c.z; v.w += c.w;
      }
      const float4 bv = *(const float4*)(bias + n0 + tid * 4);
      u.x += bv.x; u.y += bv.y; u.z += bv.z; u.w += bv.w;
      *(float4*)(ov + n0 + tid * 4) = v;
      *(float4*)(ou + n0 + tid * 4) = u;
    }
  } else if (bid < 4124) {
    const int row = (bid - 3100) * 4 + (tid >> 6);
    const int lane = tid & 63;
    const float* xr = x + (size_t)row * DMODEL + lane * 8;
    const float4 v0 = *(const float4*)(xr);
    const float4 v1 = *(const float4*)(xr + 4);
    float s  = v0.x + v0.y + v0.z + v0.w + v1.x + v1.y + v1.z + v1.w;
    float s2 = v0.x*v0.x + v0.y*v0.y + v0.z*v0.z + v0.w*v0.w
             + v1.x*v1.x + v1.y*v1.y + v1.z*v1.z + v1.w*v1.w;
    #pragma unroll
    for (int m = 1; m < 64; m <<= 1) {
      s  += __shfl_xor(s,  m);
      s2 += __shfl_xor(s2, m);
    }
    const float mu  = s * (1.0f / DMODEL);
    const float var = s2 * (1.0f / DMODEL) - mu * mu;
    const float rs  = rsqrtf(var + 1e-5f);
    if (lane == 0) stats1[row] = make_float2(mu, rs);
    u16x8 o;
    o[0] = f2bf(v0.x); o[1] = f2bf(v0.y); o[2] = f2bf(v0.z); o[3] = f2bf(v0.w);
    o[4] = f2bf(v1.x); o[5] = f2bf(v1.y); o[6] = f2bf(v1.z); o[7] = f2bf(v1.w);
    *(u16x8*)(x_bf + (size_t)row * DMODEL + lane * 8) = o;
  } else {
    const int idx = (bid - 4124) * 256 + tid;
    if (idx < 2 * NROWS) stats2[idx] = 0.0f;
  }
}

// ---------------------------------------------------------------------------
// gemm128 BK=32, 3-buffer counted-vmcnt (round-14, verified 92.18us config).
//  MODE 4: LN fold (stats1 mu/rs) -> bf16             (LN1+QKV)
//  MODE 6: LN fold (stats2 sum/sumsq) + GELU -> bf16  (LN2+FF1)
// ---------------------------------------------------------------------------
template<int MODE>
__global__ __launch_bounds__(256, 3)
void gemm128(const unsigned short* __restrict__ A,
             const unsigned short* __restrict__ Bt,
             const float* __restrict__ v, const float* __restrict__ u,
             const float* __restrict__ stats, unsigned short* __restrict__ Cb,
             int M, int N, int LDA, int KL) {
  __shared__ unsigned short smem[24576];   // 48KB

  const int tid = threadIdx.x;
  const int w = tid >> 6, l = tid & 63;
  const int gx = N >> 7;
  const int nxy = gx * (M >> 7);
  int lin = blockIdx.x;
  lin = (lin & 7) * (nxy >> 3) + (lin >> 3);  // bijective XCD swizzle (nxy%8==0)
  const int bn = (lin % gx) << 7;
  const int bm = (lin / gx) << 7;
  const int wr = (w >> 1) * 64;
  const int wc = (w & 1) * 64;
  const int lr = l & 15, kg = l >> 4;

  f32x4 acc[4][4] = {};

  auto stage = [&](int buf, int k0) {
    unsigned short* As = smem + buf * 4096;
    unsigned short* Bs = smem + 12288 + buf * 4096;
    #pragma unroll
    for (int i = 0; i < 2; ++i) {
      const int g = i * 4 + w;
      const int c = g * 64 + l;
      const int row = c >> 2;
      const int kc = (c & 3) ^ (row & 3);     // source-side pre-swizzle
      GLL16(A + (size_t)(bm + row) * LDA + k0 + kc * 8, As + g * 512);
    }
    #pragma unroll
    for (int i = 0; i < 2; ++i) {
      const int g = i * 4 + w;
      const int c = g * 64 + l;
      const int row = c >> 2;
      const int kc = (c & 3) ^ (row & 3);
      GLL16(Bt + (size_t)(bn + row) * LDA + k0 + kc * 8, Bs + g * 512);
    }
  };

  const int nt = KL >> 5;
  stage(0, 0);
  stage(1, 32);
  for (int t = 0; t < nt; ++t) {
    if (t + 1 < nt) {
      asm volatile("s_waitcnt vmcnt(4)" ::: "memory");
    } else {
      asm volatile("s_waitcnt vmcnt(0)" ::: "memory");
    }
    __builtin_amdgcn_sched_barrier(0);
    __builtin_amdgcn_s_barrier();
    __builtin_amdgcn_sched_barrier(0);
    if (t + 2 < nt) stage((t + 2) % 3, (t + 2) << 5);
    const unsigned short* As = smem + (t % 3) * 4096;
    const unsigned short* Bs = smem + 12288 + (t % 3) * 4096;
    bf16x8 af[4], bfv[4];
    #pragma unroll
    for (int mi = 0; mi < 4; ++mi) {
      const int row = wr + mi * 16 + lr;
      af[mi] = *(const bf16x8*)&As[(row * 4 + (kg ^ (row & 3))) * 8];
    }
    #pragma unroll
    for (int ni = 0; ni < 4; ++ni) {
      const int row = wc + ni * 16 + lr;
      bfv[ni] = *(const bf16x8*)&Bs[(row * 4 + (kg ^ (row & 3))) * 8];
    }
    __builtin_amdgcn_s_setprio(1);
    #pragma unroll
    for (int mi = 0; mi < 4; ++mi)
      #pragma unroll
      for (int ni = 0; ni < 4; ++ni)
        acc[mi][ni] = __builtin_amdgcn_mfma_f32_16x16x32_bf16(
            af[mi], bfv[ni], acc[mi][ni], 0, 0, 0);
    __builtin_amdgcn_s_setprio(0);
  }

  // ---- epilogue: two 32-col passes through per-wave LDS scratch ----
  __syncthreads();
  float* sc = ((float*)smem) + w * (64 * 36);
  const int r2 = l >> 2, ch = l & 3, c0 = ch * 8;
  #pragma unroll
  for (int p = 0; p < 2; ++p) {
    #pragma unroll
    for (int mi = 0; mi < 4; ++mi)
      #pragma unroll
      for (int ni = 0; ni < 2; ++ni)
        #pragma unroll
        for (int reg = 0; reg < 4; ++reg)
          sc[(mi * 16 + kg * 4 + reg) * 36 + ni * 16 + lr] = acc[mi][p * 2 + ni][reg];
    #pragma unroll
    for (int i2 = 0; i2 < 4; ++i2) {
      const int rl = i2 * 16 + r2;
      const int grow = bm + wr + rl;
      const int gcol = bn + wc + p * 32 + c0;
      const float4 va = *(const float4*)&sc[rl * 36 + c0];
      const float4 vb = *(const float4*)&sc[rl * 36 + c0 + 4];
      float vals[8] = {va.x, va.y, va.z, va.w, vb.x, vb.y, vb.z, vb.w};
      float mu, rs;
      if (MODE == 4) {
        const float2 st = ((const float2*)stats)[grow];
        mu = st.x; rs = st.y;
      } else {
        const float2 st = ((const float2*)stats)[grow];
        mu = st.x * (1.0f / DMODEL);
        rs = rsqrtf(st.y * (1.0f / DMODEL) - mu * mu + 1e-5f);
      }
      const float4 v0 = *(const float4*)&v[gcol];
      const float4 v1 = *(const float4*)&v[gcol + 4];
      const float4 u0 = *(const float4*)&u[gcol];
      const float4 u1 = *(const float4*)&u[gcol + 4];
      const float vv[8] = {v0.x, v0.y, v0.z, v0.w, v1.x, v1.y, v1.z, v1.w};
      const float uu[8] = {u0.x, u0.y, u0.z, u0.w, u1.x, u1.y, u1.z, u1.w};
      u16x8 o;
      #pragma unroll
      for (int e = 0; e < 8; ++e) {
        float t = rs * (vals[e] - mu * vv[e]) + uu[e];
        if (MODE == 6) t = 0.5f * t * (1.0f + erff(t * 0.70710678118654752f));
        o[e] = f2bf(t);
      }
      *(u16x8*)&Cb[(size_t)grow * N + gcol] = o;
    }
    if (p == 0) __builtin_amdgcn_s_barrier();
  }
}

// ---------------------------------------------------------------------------
// BM x 64 bf16 MFMA GEMM, 3-buffer counted-vmcnt pipeline (N=512 GEMMs).
// BM=64 (proven round-10): 512 blocks, 3/CU.  BM=32 (new, FF2): 1024 blocks,
// 36KB LDS -> 4/CU — doubles TLP for the latency-bound FF2 (diagnostic:
// MfmaUtil 15.7%, Occupancy 23% at 2/CU).
//  MODE 5: +bias +res(fp32) -> bf16, atomic row stats   (out-proj -> x1)
//  MODE 7: +bias +res(bf16) -> fp32                     (FF2 -> out)
// ---------------------------------------------------------------------------
template<int MODE, int BM>
__global__ __launch_bounds__(256)
void gemm_bf16(const unsigned short* __restrict__ A,
               const unsigned short* __restrict__ Bt,
               const float* __restrict__ bias,
               const float* __restrict__ resf, const unsigned short* __restrict__ resb,
               float* __restrict__ stats, void* __restrict__ Cout,
               int M, int N, int LDA, int KL) {
  constexpr int MR = BM / 32;                 // 2 (BM=64) or 1 (BM=32)
  constexpr int PS = BM / 32 + 2;             // GLLs per wave per stage
  constexpr int ROWS = BM / 2;                // wave tile rows
  __shared__ unsigned short As[3][BM * 64];
  __shared__ unsigned short Bs[3][64 * 64];

  const int tid = threadIdx.x;
  const int w = tid >> 6, l = tid & 63;
  const int gx = N >> 6;
  const int nxy = gx * (M / BM);
  int lin = blockIdx.x;
  lin = (lin & 7) * (nxy >> 3) + (lin >> 3);  // bijective XCD swizzle (nxy%8==0)
  const int bn = (lin % gx) << 6;
  const int bm = (lin / gx) * BM;
  const int wr = (w >> 1) * (BM >> 1);
  const int wc = (w & 1) * 32;
  const int lr = l & 15, kg = l >> 4;

  f32x4 acc[MR][2] = {};

  auto stage = [&](int buf, int k0) {
    #pragma unroll
    for (int i = 0; i < BM / 32; ++i) {
      const int g = i * 4 + w;
      const int c = g * 64 + l;
      const int row = c >> 3;
      const int kc = (c & 7) ^ (row & 7);
      GLL16(A + (size_t)(bm + row) * LDA + k0 + kc * 8, &As[buf][g * 512]);
    }
    #pragma unroll
    for (int i = 0; i < 2; ++i) {
      const int g = i * 4 + w;
      const int c = g * 64 + l;
      const int row = c >> 3;
      const int kc = (c & 7) ^ (row & 7);
      GLL16(Bt + (size_t)(bn + row) * LDA + k0 + kc * 8, &Bs[buf][g * 512]);
    }
  };

  const int nt = KL >> 6;
  stage(0, 0);
  stage(1, 64);
  for (int t = 0; t < nt; ++t) {
    if (t + 1 < nt) {
      asm volatile("s_waitcnt vmcnt(%0)" :: "n"(PS) : "memory");
    } else {
      asm volatile("s_waitcnt vmcnt(0)" ::: "memory");
    }
    __builtin_amdgcn_sched_barrier(0);
    __builtin_amdgcn_s_barrier();
    __builtin_amdgcn_sched_barrier(0);
    if (t + 2 < nt) stage((t + 2) % 3, (t + 2) << 6);
    const int cur = t % 3;
    #pragma unroll
    for (int ks = 0; ks < 2; ++ks) {
      const int cc = ks * 4 + kg;
      bf16x8 af[MR], bfv[2];
      #pragma unroll
      for (int mi = 0; mi < MR; ++mi) {
        const int row = wr + mi * 16 + lr;
        af[mi] = *(const bf16x8*)&As[cur][(row * 8 + (cc ^ (row & 7))) * 8];
      }
      #pragma unroll
      for (int ni = 0; ni < 2; ++ni) {
        const int row = wc + ni * 16 + lr;
        bfv[ni] = *(const bf16x8*)&Bs[cur][(row * 8 + (cc ^ (row & 7))) * 8];
      }
      __builtin_amdgcn_s_setprio(1);
      #pragma unroll
      for (int mi = 0; mi < MR; ++mi)
        #pragma unroll
        for (int ni = 0; ni < 2; ++ni)
          acc[mi][ni] = __builtin_amdgcn_mfma_f32_16x16x32_bf16(
              af[mi], bfv[ni], acc[mi][ni], 0, 0, 0);
      __builtin_amdgcn_s_setprio(0);
    }
  }

  // ---- epilogue: LDS transpose -> vectorized per-row processing ----
  __syncthreads();
  float* sc = ((float*)&As[0][0]) + w * (ROWS * 36);
  #pragma unroll
  for (int mi = 0; mi < MR; ++mi)
    #pragma unroll
    for (int ni = 0; ni < 2; ++ni)
      #pragma unroll
      for (int reg = 0; reg < 4; ++reg)
        sc[(mi * 16 + kg * 4 + reg) * 36 + ni * 16 + lr] = acc[mi][ni][reg];

  float* Cf = (float*)Cout;
  unsigned short* Cb = (unsigned short*)Cout;
  const int r2 = l >> 2, ch = l & 3;
  #pragma unroll
  for (int i2 = 0; i2 < ROWS / 16; ++i2) {
    const int rl = i2 * 16 + r2;
    const int grow = bm + wr + rl;
    const int c0 = ch * 8;
    const int gcol = bn + wc + c0;
    const float4 va = *(const float4*)&sc[rl * 36 + c0];
    const float4 vb = *(const float4*)&sc[rl * 36 + c0 + 4];
    float vals[8] = {va.x, va.y, va.z, va.w, vb.x, vb.y, vb.z, vb.w};

    if (MODE == 5) {
      const float4 b0 = *(const float4*)&bias[gcol];
      const float4 b1 = *(const float4*)&bias[gcol + 4];
      const float4 r0 = *(const float4*)&resf[(size_t)grow * N + gcol];
      const float4 r1 = *(const float4*)&resf[(size_t)grow * N + gcol + 4];
      const float bb[8] = {b0.x, b0.y, b0.z, b0.w, b1.x, b1.y, b1.z, b1.w};
      const float rr[8] = {r0.x, r0.y, r0.z, r0.w, r1.x, r1.y, r1.z, r1.w};
      float rsum = 0.0f, rsq = 0.0f;
      u16x8 o;
      #pragma unroll
      for (int e = 0; e < 8; ++e) {
        const float t = vals[e] + bb[e] + rr[e];
        o[e] = f2bf(t);
        rsum += t; rsq = fmaf(t, t, rsq);
      }
      *(u16x8*)&Cb[(size_t)grow * N + gcol] = o;
      rsum += __shfl_xor(rsum, 1); rsq += __shfl_xor(rsq, 1);
      rsum += __shfl_xor(rsum, 2); rsq += __shfl_xor(rsq, 2);
      if (ch == 0) {
        atomicAdd(&stats[2 * grow],     rsum);
        atomicAdd(&stats[2 * grow + 1], rsq);
      }
    }

    if (MODE == 7) {
      const float4 b0 = *(const float4*)&bias[gcol];
      const float4 b1 = *(const float4*)&bias[gcol + 4];
      const u16x8 rb = *(const u16x8*)&resb[(size_t)grow * N + gcol];
      const float bb[8] = {b0.x, b0.y, b0.z, b0.w, b1.x, b1.y, b1.z, b1.w};
      #pragma unroll
      for (int e = 0; e < 8; ++e) vals[e] += bb[e] + bf2f(rb[e]);
      *(float4*)&Cf[(size_t)grow * N + gcol] =
          make_float4(vals[0], vals[1], vals[2], vals[3]);
      *(float4*)&Cf[(size_t)grow * N + gcol + 4] =
          make_float4(vals[4], vals[5], vals[6], vals[7]);
    }
  }
}

// ---------------------------------------------------------------------------
// Sparse geometric attention (round-13 version, XCD-swizzled).
// ---------------------------------------------------------------------------
#define CAP 256
__global__ __launch_bounds__(64)
void attn_kernel(const unsigned short* __restrict__ qkv,
                 const int* __restrict__ pos, const int* __restrict__ lvl,
                 unsigned short* __restrict__ out) {
  const int bid = blockIdx.x;
  const int r = (bid & 7) * (NROWS / 8) + (bid >> 3);
  const int i = r & (NSEQ - 1);
  const int base = r - i;
  const int lane = threadIdx.x;

  __shared__ int   s_idx[CAP];
  __shared__ int   s_cnt;
  __shared__ float s_sc[NHEADS][CAP];
  __shared__ float s_inv[NHEADS];

  if (lane == 0) s_cnt = 0;
  __syncthreads();

  const int li = lvl[r];
  const int2 pq = *(const int2*)(pos + 2 * r);
  const int win = (li == 0) ? 512 : (li == 1 ? 64 : 16);
  const int jlo = max(i - win + 1, 0);
  const int jhi = min(i + win - 1, NSEQ - 1);

  for (int j = jlo + lane; j <= jhi; j += 64) {
    const int rj = base + j;
    bool m = (j == i);
    if (!m) {
      const int lj = lvl[rj];
      const int2 pj = *(const int2*)(pos + 2 * rj);
      const int d = abs(pq.x - pj.x) + abs(pq.y - pj.y);
      m = (lj == li) && (d <= 1);
    }
    if (m) {
      const int p = atomicAdd(&s_cnt, 1);
      if (p < CAP) s_idx[p] = j;
    }
  }
  __syncthreads();
  const int cnt = min(s_cnt, CAP);

  const u16x8 qv = *(const u16x8*)(qkv + (size_t)r * 1536 + lane * 8);
  float qf[8];
  #pragma unroll
  for (int e = 0; e < 8; ++e) qf[e] = bf2f(qv[e]);

  for (int jj = 0; jj < cnt; ++jj) {
    const int rj = base + s_idx[jj];
    const u16x8 kv = *(const u16x8*)(qkv + (size_t)rj * 1536 + 512 + lane * 8);
    float p = 0.0f;
    #pragma unroll
    for (int e = 0; e < 8; ++e) p = fmaf(qf[e], bf2f(kv[e]), p);
    p += __shfl_xor(p, 1);
    p += __shfl_xor(p, 2);
    p += __shfl_xor(p, 4);
    if ((lane & 7) == 0) s_sc[lane >> 3][jj] = p * 0.125f;
  }
  __syncthreads();

  if (lane < 8) {
    float mx = -1e30f;
    for (int jj = 0; jj < cnt; ++jj) mx = fmaxf(mx, s_sc[lane][jj]);
    float den = 0.0f;
    for (int jj = 0; jj < cnt; ++jj) {
      const float e = expf(s_sc[lane][jj] - mx);
      s_sc[lane][jj] = e;
      den += e;
    }
    s_inv[lane] = 1.0f / den;
  }
  __syncthreads();

  const int h = lane >> 3;
  float a[8] = {};
  for (int jj = 0; jj < cnt; ++jj) {
    const float pp = s_sc[h][jj];
    const u16x8 vv = *(const u16x8*)(qkv + (size_t)(base + s_idx[jj]) * 1536 + 1024 + lane * 8);
    #pragma unroll
    for (int e = 0; e < 8; ++e) a[e] = fmaf(pp, bf2f(vv[e]), a[e]);
  }
  const float inv = s_inv[h];
  u16x8 o;
  #pragma unroll
  for (int e = 0; e < 8; ++e) o[e] = f2bf(a[e] * inv);
  *(u16x8*)(out + (size_t)r * DMODEL + lane * 8) = o;
}

// ---------------------------------------------------------------------------
extern "C" void kernel_launch(void* const* d_in, const int* in_sizes, int n_in,
                              void* d_out, int out_size, void* d_ws, size_t ws_size,
                              hipStream_t stream) {
  const float* x            = (const float*)d_in[0];
  const int*   coords_pos   = (const int*)d_in[1];
  const int*   coords_level = (const int*)d_in[2];
  const float* w_qkv        = (const float*)d_in[3];
  const float* b_qkv        = (const float*)d_in[4];
  const float* w_out        = (const float*)d_in[5];
  const float* b_out        = (const float*)d_in[6];
  const float* w_ff1        = (const float*)d_in[7];
  const float* b_ff1        = (const float*)d_in[8];
  const float* w_ff2        = (const float*)d_in[9];
  const float* b_ff2        = (const float*)d_in[10];
  const float* ln1_g        = (const float*)d_in[11];
  const float* ln1_b        = (const float*)d_in[12];
  const float* ln2_g        = (const float*)d_in[13];
  const float* ln2_b        = (const float*)d_in[14];
  float* out = (float*)d_out;

  // workspace layout (bytes)
  char* ws = (char*)d_ws;
  unsigned short* qkv_bf = (unsigned short*)(ws);
  unsigned short* h_bf   = (unsigned short*)(ws);
  unsigned short* x_bf   = (unsigned short*)(ws + 16777216);
  unsigned short* at_bf  = (unsigned short*)(ws + 20971520);
  unsigned short* x1_bf  = (unsigned short*)(ws + 25165824);
  unsigned short* wqkvT  = (unsigned short*)(ws + 29360128);
  unsigned short* woutT  = (unsigned short*)(ws + 30932992);
  unsigned short* wff1T  = (unsigned short*)(ws + 31457280);
  unsigned short* wff2T  = (unsigned short*)(ws + 33554432);
  float*          vq     = (float*)(ws + 35651584);
  float*          uq     = (float*)(ws + 35657728);
  float*          vf     = (float*)(ws + 35663872);
  float*          uf     = (float*)(ws + 35672064);
  float2*         stats1 = (float2*)(ws + 35680256);
  float*          stats2 = (float*)(ws + 35713024);

  // 1. prep
  prep<<<4156, 256, 0, stream>>>(w_qkv, w_out, w_ff1, w_ff2,
                                 ln1_g, ln1_b, ln2_g, ln2_b, b_qkv, b_ff1, x,
                                 wqkvT, woutT, wff1T, wff2T,
                                 vq, uq, vf, uf, x_bf, stats1, stats2);

  // 2. LN1+QKV fused -> bf16   (128x128 tiles, 384 blocks, 3/CU)
  gemm128<4><<<(1536/128)*(NROWS/128), 256, 0, stream>>>(
      x_bf, wqkvT, vq, uq, (const float*)stats1, qkv_bf, NROWS, 1536, DMODEL, DMODEL);

  // 3. sparse geometric attention -> bf16 (XCD-swizzled)
  attn_kernel<<<NROWS, 64, 0, stream>>>(qkv_bf, coords_pos, coords_level, at_bf);

  // 4. out-proj + residual(x fp32) -> x1 bf16, atomic row stats (512 blocks, 3/CU)
  gemm_bf16<5, 64><<<(DMODEL/64)*(NROWS/64), 256, 0, stream>>>(
      at_bf, woutT, b_out, x, nullptr, stats2, x1_bf, NROWS, DMODEL, DMODEL, DMODEL);

  // 5. LN2+FF1+GELU fused -> bf16   (128x128 tiles, 512 blocks, 3/CU)
  gemm128<6><<<(DFF/128)*(NROWS/128), 256, 0, stream>>>(
      x1_bf, wff1T, vf, uf, stats2, h_bf, NROWS, DFF, DMODEL, DMODEL);

  // 6. FF2 + residual(x1 bf16) -> d_out fp32   (BM=32: 1024 blocks, 4/CU)
  gemm_bf16<7, 32><<<(DMODEL/64)*(NROWS/32), 256, 0, stream>>>(
      h_bf, wff2T, b_ff2, nullptr, x1_bf, nullptr, out, NROWS, DMODEL, DFF, DFF);
}

// Round 20
// 89.859 us; speedup vs baseline: 6.4765x; 1.0001x over previous
//
#include <hip/hip_runtime.h>
#include <hip/hip_bf16.h>

#define DMODEL 512
#define NHEADS 8
#define DFF 2048
#define NSEQ 2048
#define NROWS 4096

typedef __attribute__((ext_vector_type(8))) short   bf16x8;   // MFMA A/B frag
typedef __attribute__((ext_vector_type(4))) float   f32x4;    // MFMA C/D frag
typedef __attribute__((ext_vector_type(8))) unsigned short u16x8;

__device__ __forceinline__ unsigned short f2bf(float f) {
  union { float f; unsigned u; } v; v.f = f;
  unsigned r = v.u + 0x7fffu + ((v.u >> 16) & 1u);   // RNE
  return (unsigned short)(r >> 16);
}
__device__ __forceinline__ float bf2f(unsigned short u) {
  union { unsigned u; float f; } v; v.u = (unsigned)u << 16;
  return v.f;
}

#define GLL16(src, dst) \
  __builtin_amdgcn_global_load_lds((__attribute__((address_space(1))) const void*)(src), \
                                   (__attribute__((address_space(3))) void*)(dst), 16, 0, 0)

// ---------------------------------------------------------------------------
// prep: weight transposes (+gamma fold), u/v colsums, x stats + bf16 cast,
// stats2 zero. (round-14 version)
// ---------------------------------------------------------------------------
__global__ __launch_bounds__(256)
void prep(const float* __restrict__ w_qkv, const float* __restrict__ w_out,
          const float* __restrict__ w_ff1, const float* __restrict__ w_ff2,
          const float* __restrict__ ln1_g, const float* __restrict__ ln1_b,
          const float* __restrict__ ln2_g, const float* __restrict__ ln2_b,
          const float* __restrict__ b_qkv, const float* __restrict__ b_ff1,
          const float* __restrict__ x,
          unsigned short* __restrict__ wqkvT, unsigned short* __restrict__ woutT,
          unsigned short* __restrict__ wff1T, unsigned short* __restrict__ wff2T,
          float* __restrict__ vq, float* __restrict__ uq,
          float* __restrict__ vf, float* __restrict__ uf,
          unsigned short* __restrict__ x_bf, float2* __restrict__ stats1,
          float* __restrict__ stats2) {
  __shared__ char smem_raw[12288];
  int bid = blockIdx.x;
  const int tid = threadIdx.x;
  if (bid < 3072) {
    unsigned short (*t)[33] = (unsigned short (*)[33])smem_raw;
    const float* w; unsigned short* wT; const float* g; int K, N;
    if (bid < 768)       { w = w_qkv; wT = wqkvT; g = ln1_g; K = 512;  N = 1536; }
    else if (bid < 1024) { bid -= 768;  w = w_out; wT = woutT; g = nullptr; K = 512;  N = 512; }
    else if (bid < 2048) { bid -= 1024; w = w_ff1; wT = wff1T; g = ln2_g; K = 512;  N = 2048; }
    else                 { bid -= 2048; w = w_ff2; wT = wff2T; g = nullptr; K = 2048; N = 512; }
    const int ntx = N >> 5;
    const int n0 = (bid % ntx) * 32, k0 = (bid / ntx) * 32;
    const int tx = tid & 31, ty = tid >> 5;
    #pragma unroll
    for (int i = 0; i < 4; ++i) {
      const int k = k0 + ty + i * 8;
      const float s = g ? g[k] : 1.0f;
      t[ty + i * 8][tx] = f2bf(s * w[(size_t)k * N + n0 + tx]);
    }
    __syncthreads();
    #pragma unroll
    for (int i = 0; i < 4; ++i)
      wT[(size_t)(n0 + ty + i * 8) * K + k0 + tx] = t[tx][ty + i * 8];
  } else if (bid < 3100) {
    const int b = bid - 3072;
    const float *w, *g, *bb, *bias; float *ov, *ou; int N, n0;
    if (b < 12) { w = w_qkv; g = ln1_g; bb = ln1_b; bias = b_qkv;
                  ov = vq; ou = uq; N = 1536; n0 = b * 128; }
    else        { w = w_ff1; g = ln2_g; bb = ln2_b; bias = b_ff1;
                  ov = vf; ou = uf; N = 2048; n0 = (b - 12) * 128; }
    float*  sg = (float*)smem_raw;
    float*  sb = sg + 512;
    float4* pu = (float4*)(sb + 512);
    float4* pv = pu + 256;
    sg[tid] = g[tid];  sg[tid + 256] = g[tid + 256];
    sb[tid] = bb[tid]; sb[tid + 256] = bb[tid + 256];
    __syncthreads();
    const int c4 = tid & 31, kg = tid >> 5;
    float4 su = make_float4(0, 0, 0, 0), sv = make_float4(0, 0, 0, 0);
    const float* wp = w + (size_t)(kg * 64) * N + n0 + c4 * 4;
    #pragma unroll 8
    for (int kk = 0; kk < 64; ++kk) {
      const float4 wv = *(const float4*)(wp + (size_t)kk * N);
      const float gk = sg[kg * 64 + kk], bk = sb[kg * 64 + kk];
      su.x = fmaf(bk, wv.x, su.x); su.y = fmaf(bk, wv.y, su.y);
      su.z = fmaf(bk, wv.z, su.z); su.w = fmaf(bk, wv.w, su.w);
      sv.x = fmaf(gk, wv.x, sv.x); sv.y = fmaf(gk, wv.y, sv.y);
      sv.z = fmaf(gk, wv.z, sv.z); sv.w = fmaf(gk, wv.w, sv.w);
    }
    pu[kg * 32 + c4] = su; pv[kg * 32 + c4] = sv;
    __syncthreads();
    if (tid < 32) {
      float4 u = pu[tid], v = pv[tid];
      #pragma unroll
      for (int q = 1; q < 8; ++q) {
        const float4 a = pu[q * 32 + tid], c = pv[q * 32 + tid];
        u.x += a.x; u.y += a.y; u.z += a.z; u.w += a.w;
        v.x += c.x; v.y += c.y; v.z += c.z; v.w += c.w;
      }
      const float4 bv = *(const float4*)(bias + n0 + tid * 4);
      u.x += bv.x; u.y += bv.y; u.z += bv.z; u.w += bv.w;
      *(float4*)(ov + n0 + tid * 4) = v;
      *(float4*)(ou + n0 + tid * 4) = u;
    }
  } else if (bid < 4124) {
    const int row = (bid - 3100) * 4 + (tid >> 6);
    const int lane = tid & 63;
    const float* xr = x + (size_t)row * DMODEL + lane * 8;
    const float4 v0 = *(const float4*)(xr);
    const float4 v1 = *(const float4*)(xr + 4);
    float s  = v0.x + v0.y + v0.z + v0.w + v1.x + v1.y + v1.z + v1.w;
    float s2 = v0.x*v0.x + v0.y*v0.y + v0.z*v0.z + v0.w*v0.w
             + v1.x*v1.x + v1.y*v1.y + v1.z*v1.z + v1.w*v1.w;
    #pragma unroll
    for (int m = 1; m < 64; m <<= 1) {
      s  += __shfl_xor(s,  m);
      s2 += __shfl_xor(s2, m);
    }
    const float mu  = s * (1.0f / DMODEL);
    const float var = s2 * (1.0f / DMODEL) - mu * mu;
    const float rs  = rsqrtf(var + 1e-5f);
    if (lane == 0) stats1[row] = make_float2(mu, rs);
    u16x8 o;
    o[0] = f2bf(v0.x); o[1] = f2bf(v0.y); o[2] = f2bf(v0.z); o[3] = f2bf(v0.w);
    o[4] = f2bf(v1.x); o[5] = f2bf(v1.y); o[6] = f2bf(v1.z); o[7] = f2bf(v1.w);
    *(u16x8*)(x_bf + (size_t)row * DMODEL + lane * 8) = o;
  } else {
    const int idx = (bid - 4124) * 256 + tid;
    if (idx < 2 * NROWS) stats2[idx] = 0.0f;
  }
}

// ---------------------------------------------------------------------------
// gemm128 BK=32, 3-buffer counted-vmcnt (round-14, verified).
//  MODE 4: LN fold (stats1 mu/rs) -> bf16             (LN1+QKV)
//  MODE 6: LN fold (stats2 sum/sumsq) + GELU -> bf16  (LN2+FF1)
// ---------------------------------------------------------------------------
template<int MODE>
__global__ __launch_bounds__(256, 3)
void gemm128(const unsigned short* __restrict__ A,
             const unsigned short* __restrict__ Bt,
             const float* __restrict__ v, const float* __restrict__ u,
             const float* __restrict__ stats, unsigned short* __restrict__ Cb,
             int M, int N, int LDA, int KL) {
  __shared__ unsigned short smem[24576];   // 48KB

  const int tid = threadIdx.x;
  const int w = tid >> 6, l = tid & 63;
  const int gx = N >> 7;
  const int nxy = gx * (M >> 7);
  int lin = blockIdx.x;
  lin = (lin & 7) * (nxy >> 3) + (lin >> 3);  // bijective XCD swizzle (nxy%8==0)
  const int bn = (lin % gx) << 7;
  const int bm = (lin / gx) << 7;
  const int wr = (w >> 1) * 64;
  const int wc = (w & 1) * 64;
  const int lr = l & 15, kg = l >> 4;

  f32x4 acc[4][4] = {};

  auto stage = [&](int buf, int k0) {
    unsigned short* As = smem + buf * 4096;
    unsigned short* Bs = smem + 12288 + buf * 4096;
    #pragma unroll
    for (int i = 0; i < 2; ++i) {
      const int g = i * 4 + w;
      const int c = g * 64 + l;
      const int row = c >> 2;
      const int kc = (c & 3) ^ (row & 3);     // source-side pre-swizzle
      GLL16(A + (size_t)(bm + row) * LDA + k0 + kc * 8, As + g * 512);
    }
    #pragma unroll
    for (int i = 0; i < 2; ++i) {
      const int g = i * 4 + w;
      const int c = g * 64 + l;
      const int row = c >> 2;
      const int kc = (c & 3) ^ (row & 3);
      GLL16(Bt + (size_t)(bn + row) * LDA + k0 + kc * 8, Bs + g * 512);
    }
  };

  const int nt = KL >> 5;
  stage(0, 0);
  stage(1, 32);
  for (int t = 0; t < nt; ++t) {
    if (t + 1 < nt) {
      asm volatile("s_waitcnt vmcnt(4)" ::: "memory");
    } else {
      asm volatile("s_waitcnt vmcnt(0)" ::: "memory");
    }
    __builtin_amdgcn_sched_barrier(0);
    __builtin_amdgcn_s_barrier();
    __builtin_amdgcn_sched_barrier(0);
    if (t + 2 < nt) stage((t + 2) % 3, (t + 2) << 5);
    const unsigned short* As = smem + (t % 3) * 4096;
    const unsigned short* Bs = smem + 12288 + (t % 3) * 4096;
    bf16x8 af[4], bfv[4];
    #pragma unroll
    for (int mi = 0; mi < 4; ++mi) {
      const int row = wr + mi * 16 + lr;
      af[mi] = *(const bf16x8*)&As[(row * 4 + (kg ^ (row & 3))) * 8];
    }
    #pragma unroll
    for (int ni = 0; ni < 4; ++ni) {
      const int row = wc + ni * 16 + lr;
      bfv[ni] = *(const bf16x8*)&Bs[(row * 4 + (kg ^ (row & 3))) * 8];
    }
    __builtin_amdgcn_s_setprio(1);
    #pragma unroll
    for (int mi = 0; mi < 4; ++mi)
      #pragma unroll
      for (int ni = 0; ni < 4; ++ni)
        acc[mi][ni] = __builtin_amdgcn_mfma_f32_16x16x32_bf16(
            af[mi], bfv[ni], acc[mi][ni], 0, 0, 0);
    __builtin_amdgcn_s_setprio(0);
  }

  // ---- epilogue: two 32-col passes through per-wave LDS scratch ----
  __syncthreads();
  float* sc = ((float*)smem) + w * (64 * 36);
  const int r2 = l >> 2, ch = l & 3, c0 = ch * 8;
  #pragma unroll
  for (int p = 0; p < 2; ++p) {
    #pragma unroll
    for (int mi = 0; mi < 4; ++mi)
      #pragma unroll
      for (int ni = 0; ni < 2; ++ni)
        #pragma unroll
        for (int reg = 0; reg < 4; ++reg)
          sc[(mi * 16 + kg * 4 + reg) * 36 + ni * 16 + lr] = acc[mi][p * 2 + ni][reg];
    #pragma unroll
    for (int i2 = 0; i2 < 4; ++i2) {
      const int rl = i2 * 16 + r2;
      const int grow = bm + wr + rl;
      const int gcol = bn + wc + p * 32 + c0;
      const float4 va = *(const float4*)&sc[rl * 36 + c0];
      const float4 vb = *(const float4*)&sc[rl * 36 + c0 + 4];
      float vals[8] = {va.x, va.y, va.z, va.w, vb.x, vb.y, vb.z, vb.w};
      float mu, rs;
      if (MODE == 4) {
        const float2 st = ((const float2*)stats)[grow];
        mu = st.x; rs = st.y;
      } else {
        const float2 st = ((const float2*)stats)[grow];
        mu = st.x * (1.0f / DMODEL);
        rs = rsqrtf(st.y * (1.0f / DMODEL) - mu * mu + 1e-5f);
      }
      const float4 v0 = *(const float4*)&v[gcol];
      const float4 v1 = *(const float4*)&v[gcol + 4];
      const float4 u0 = *(const float4*)&u[gcol];
      const float4 u1 = *(const float4*)&u[gcol + 4];
      const float vv[8] = {v0.x, v0.y, v0.z, v0.w, v1.x, v1.y, v1.z, v1.w};
      const float uu[8] = {u0.x, u0.y, u0.z, u0.w, u1.x, u1.y, u1.z, u1.w};
      u16x8 o;
      #pragma unroll
      for (int e = 0; e < 8; ++e) {
        float t = rs * (vals[e] - mu * vv[e]) + uu[e];
        if (MODE == 6) t = 0.5f * t * (1.0f + erff(t * 0.70710678118654752f));
        o[e] = f2bf(t);
      }
      *(u16x8*)&Cb[(size_t)grow * N + gcol] = o;
    }
    if (p == 0) __builtin_amdgcn_s_barrier();
  }
}

// ---------------------------------------------------------------------------
// BM x 64 bf16 MFMA GEMM, 3-buffer counted-vmcnt pipeline (N=512 GEMMs).
// BM=32: 1024 blocks, 36KB LDS -> 4 blocks/CU (the one lever that moves
// these latency-bound shapes; FF2 precedent round 19: -2.3us).
//  MODE 5: +bias +res(fp32) -> bf16, atomic row stats   (out-proj -> x1)
//  MODE 7: +bias +res(bf16) -> fp32                     (FF2 -> out)
// ---------------------------------------------------------------------------
template<int MODE, int BM>
__global__ __launch_bounds__(256)
void gemm_bf16(const unsigned short* __restrict__ A,
               const unsigned short* __restrict__ Bt,
               const float* __restrict__ bias,
               const float* __restrict__ resf, const unsigned short* __restrict__ resb,
               float* __restrict__ stats, void* __restrict__ Cout,
               int M, int N, int LDA, int KL) {
  constexpr int MR = BM / 32;                 // 1 (BM=32)
  constexpr int PS = BM / 32 + 2;             // GLLs per wave per stage
  constexpr int ROWS = BM / 2;                // wave tile rows
  __shared__ unsigned short As[3][BM * 64];
  __shared__ unsigned short Bs[3][64 * 64];

  const int tid = threadIdx.x;
  const int w = tid >> 6, l = tid & 63;
  const int gx = N >> 6;
  const int nxy = gx * (M / BM);
  int lin = blockIdx.x;
  lin = (lin & 7) * (nxy >> 3) + (lin >> 3);  // bijective XCD swizzle (nxy%8==0)
  const int bn = (lin % gx) << 6;
  const int bm = (lin / gx) * BM;
  const int wr = (w >> 1) * (BM >> 1);
  const int wc = (w & 1) * 32;
  const int lr = l & 15, kg = l >> 4;

  f32x4 acc[MR][2] = {};

  auto stage = [&](int buf, int k0) {
    #pragma unroll
    for (int i = 0; i < BM / 32; ++i) {
      const int g = i * 4 + w;
      const int c = g * 64 + l;
      const int row = c >> 3;
      const int kc = (c & 7) ^ (row & 7);
      GLL16(A + (size_t)(bm + row) * LDA + k0 + kc * 8, &As[buf][g * 512]);
    }
    #pragma unroll
    for (int i = 0; i < 2; ++i) {
      const int g = i * 4 + w;
      const int c = g * 64 + l;
      const int row = c >> 3;
      const int kc = (c & 7) ^ (row & 7);
      GLL16(Bt + (size_t)(bn + row) * LDA + k0 + kc * 8, &Bs[buf][g * 512]);
    }
  };

  const int nt = KL >> 6;
  stage(0, 0);
  stage(1, 64);
  for (int t = 0; t < nt; ++t) {
    if (t + 1 < nt) {
      asm volatile("s_waitcnt vmcnt(%0)" :: "n"(PS) : "memory");
    } else {
      asm volatile("s_waitcnt vmcnt(0)" ::: "memory");
    }
    __builtin_amdgcn_sched_barrier(0);
    __builtin_amdgcn_s_barrier();
    __builtin_amdgcn_sched_barrier(0);
    if (t + 2 < nt) stage((t + 2) % 3, (t + 2) << 6);
    const int cur = t % 3;
    #pragma unroll
    for (int ks = 0; ks < 2; ++ks) {
      const int cc = ks * 4 + kg;
      bf16x8 af[MR], bfv[2];
      #pragma unroll
      for (int mi = 0; mi < MR; ++mi) {
        const int row = wr + mi * 16 + lr;
        af[mi] = *(const bf16x8*)&As[cur][(row * 8 + (cc ^ (row & 7))) * 8];
      }
      #pragma unroll
      for (int ni = 0; ni < 2; ++ni) {
        const int row = wc + ni * 16 + lr;
        bfv[ni] = *(const bf16x8*)&Bs[cur][(row * 8 + (cc ^ (row & 7))) * 8];
      }
      __builtin_amdgcn_s_setprio(1);
      #pragma unroll
      for (int mi = 0; mi < MR; ++mi)
        #pragma unroll
        for (int ni = 0; ni < 2; ++ni)
          acc[mi][ni] = __builtin_amdgcn_mfma_f32_16x16x32_bf16(
              af[mi], bfv[ni], acc[mi][ni], 0, 0, 0);
      __builtin_amdgcn_s_setprio(0);
    }
  }

  // ---- epilogue: LDS transpose -> vectorized per-row processing ----
  __syncthreads();
  float* sc = ((float*)&As[0][0]) + w * (ROWS * 36);
  #pragma unroll
  for (int mi = 0; mi < MR; ++mi)
    #pragma unroll
    for (int ni = 0; ni < 2; ++ni)
      #pragma unroll
      for (int reg = 0; reg < 4; ++reg)
        sc[(mi * 16 + kg * 4 + reg) * 36 + ni * 16 + lr] = acc[mi][ni][reg];

  float* Cf = (float*)Cout;
  unsigned short* Cb = (unsigned short*)Cout;
  const int r2 = l >> 2, ch = l & 3;
  #pragma unroll
  for (int i2 = 0; i2 < ROWS / 16; ++i2) {
    const int rl = i2 * 16 + r2;
    const int grow = bm + wr + rl;
    const int c0 = ch * 8;
    const int gcol = bn + wc + c0;
    const float4 va = *(const float4*)&sc[rl * 36 + c0];
    const float4 vb = *(const float4*)&sc[rl * 36 + c0 + 4];
    float vals[8] = {va.x, va.y, va.z, va.w, vb.x, vb.y, vb.z, vb.w};

    if (MODE == 5) {
      const float4 b0 = *(const float4*)&bias[gcol];
      const float4 b1 = *(const float4*)&bias[gcol + 4];
      const float4 r0 = *(const float4*)&resf[(size_t)grow * N + gcol];
      const float4 r1 = *(const float4*)&resf[(size_t)grow * N + gcol + 4];
      const float bb[8] = {b0.x, b0.y, b0.z, b0.w, b1.x, b1.y, b1.z, b1.w};
      const float rr[8] = {r0.x, r0.y, r0.z, r0.w, r1.x, r1.y, r1.z, r1.w};
      float rsum = 0.0f, rsq = 0.0f;
      u16x8 o;
      #pragma unroll
      for (int e = 0; e < 8; ++e) {
        const float t = vals[e] + bb[e] + rr[e];
        o[e] = f2bf(t);
        rsum += t; rsq = fmaf(t, t, rsq);
      }
      *(u16x8*)&Cb[(size_t)grow * N + gcol] = o;
      rsum += __shfl_xor(rsum, 1); rsq += __shfl_xor(rsq, 1);
      rsum += __shfl_xor(rsum, 2); rsq += __shfl_xor(rsq, 2);
      if (ch == 0) {
        atomicAdd(&stats[2 * grow],     rsum);
        atomicAdd(&stats[2 * grow + 1], rsq);
      }
    }

    if (MODE == 7) {
      const float4 b0 = *(const float4*)&bias[gcol];
      const float4 b1 = *(const float4*)&bias[gcol + 4];
      const u16x8 rb = *(const u16x8*)&resb[(size_t)grow * N + gcol];
      const float bb[8] = {b0.x, b0.y, b0.z, b0.w, b1.x, b1.y, b1.z, b1.w};
      #pragma unroll
      for (int e = 0; e < 8; ++e) vals[e] += bb[e] + bf2f(rb[e]);
      *(float4*)&Cf[(size_t)grow * N + gcol] =
          make_float4(vals[0], vals[1], vals[2], vals[3]);
      *(float4*)&Cf[(size_t)grow * N + gcol + 4] =
          make_float4(vals[4], vals[5], vals[6], vals[7]);
    }
  }
}

// ---------------------------------------------------------------------------
// Sparse geometric attention (round-13 version, XCD-swizzled).
// ---------------------------------------------------------------------------
#define CAP 256
__global__ __launch_bounds__(64)
void attn_kernel(const unsigned short* __restrict__ qkv,
                 const int* __restrict__ pos, const int* __restrict__ lvl,
                 unsigned short* __restrict__ out) {
  const int bid = blockIdx.x;
  const int r = (bid & 7) * (NROWS / 8) + (bid >> 3);
  const int i = r & (NSEQ - 1);
  const int base = r - i;
  const int lane = threadIdx.x;

  __shared__ int   s_idx[CAP];
  __shared__ int   s_cnt;
  __shared__ float s_sc[NHEADS][CAP];
  __shared__ float s_inv[NHEADS];

  if (lane == 0) s_cnt = 0;
  __syncthreads();

  const int li = lvl[r];
  const int2 pq = *(const int2*)(pos + 2 * r);
  const int win = (li == 0) ? 512 : (li == 1 ? 64 : 16);
  const int jlo = max(i - win + 1, 0);
  const int jhi = min(i + win - 1, NSEQ - 1);

  for (int j = jlo + lane; j <= jhi; j += 64) {
    const int rj = base + j;
    bool m = (j == i);
    if (!m) {
      const int lj = lvl[rj];
      const int2 pj = *(const int2*)(pos + 2 * rj);
      const int d = abs(pq.x - pj.x) + abs(pq.y - pj.y);
      m = (lj == li) && (d <= 1);
    }
    if (m) {
      const int p = atomicAdd(&s_cnt, 1);
      if (p < CAP) s_idx[p] = j;
    }
  }
  __syncthreads();
  const int cnt = min(s_cnt, CAP);

  const u16x8 qv = *(const u16x8*)(qkv + (size_t)r * 1536 + lane * 8);
  float qf[8];
  #pragma unroll
  for (int e = 0; e < 8; ++e) qf[e] = bf2f(qv[e]);

  for (int jj = 0; jj < cnt; ++jj) {
    const int rj = base + s_idx[jj];
    const u16x8 kv = *(const u16x8*)(qkv + (size_t)rj * 1536 + 512 + lane * 8);
    float p = 0.0f;
    #pragma unroll
    for (int e = 0; e < 8; ++e) p = fmaf(qf[e], bf2f(kv[e]), p);
    p += __shfl_xor(p, 1);
    p += __shfl_xor(p, 2);
    p += __shfl_xor(p, 4);
    if ((lane & 7) == 0) s_sc[lane >> 3][jj] = p * 0.125f;
  }
  __syncthreads();

  if (lane < 8) {
    float mx = -1e30f;
    for (int jj = 0; jj < cnt; ++jj) mx = fmaxf(mx, s_sc[lane][jj]);
    float den = 0.0f;
    for (int jj = 0; jj < cnt; ++jj) {
      const float e = expf(s_sc[lane][jj] - mx);
      s_sc[lane][jj] = e;
      den += e;
    }
    s_inv[lane] = 1.0f / den;
  }
  __syncthreads();

  const int h = lane >> 3;
  float a[8] = {};
  for (int jj = 0; jj < cnt; ++jj) {
    const float pp = s_sc[h][jj];
    const u16x8 vv = *(const u16x8*)(qkv + (size_t)(base + s_idx[jj]) * 1536 + 1024 + lane * 8);
    #pragma unroll
    for (int e = 0; e < 8; ++e) a[e] = fmaf(pp, bf2f(vv[e]), a[e]);
  }
  const float inv = s_inv[h];
  u16x8 o;
  #pragma unroll
  for (int e = 0; e < 8; ++e) o[e] = f2bf(a[e] * inv);
  *(u16x8*)(out + (size_t)r * DMODEL + lane * 8) = o;
}

// ---------------------------------------------------------------------------
extern "C" void kernel_launch(void* const* d_in, const int* in_sizes, int n_in,
                              void* d_out, int out_size, void* d_ws, size_t ws_size,
                              hipStream_t stream) {
  const float* x            = (const float*)d_in[0];
  const int*   coords_pos   = (const int*)d_in[1];
  const int*   coords_level = (const int*)d_in[2];
  const float* w_qkv        = (const float*)d_in[3];
  const float* b_qkv        = (const float*)d_in[4];
  const float* w_out        = (const float*)d_in[5];
  const float* b_out        = (const float*)d_in[6];
  const float* w_ff1        = (const float*)d_in[7];
  const float* b_ff1        = (const float*)d_in[8];
  const float* w_ff2        = (const float*)d_in[9];
  const float* b_ff2        = (const float*)d_in[10];
  const float* ln1_g        = (const float*)d_in[11];
  const float* ln1_b        = (const float*)d_in[12];
  const float* ln2_g        = (const float*)d_in[13];
  const float* ln2_b        = (const float*)d_in[14];
  float* out = (float*)d_out;

  // workspace layout (bytes)
  char* ws = (char*)d_ws;
  unsigned short* qkv_bf = (unsigned short*)(ws);
  unsigned short* h_bf   = (unsigned short*)(ws);
  unsigned short* x_bf   = (unsigned short*)(ws + 16777216);
  unsigned short* at_bf  = (unsigned short*)(ws + 20971520);
  unsigned short* x1_bf  = (unsigned short*)(ws + 25165824);
  unsigned short* wqkvT  = (unsigned short*)(ws + 29360128);
  unsigned short* woutT  = (unsigned short*)(ws + 30932992);
  unsigned short* wff1T  = (unsigned short*)(ws + 31457280);
  unsigned short* wff2T  = (unsigned short*)(ws + 33554432);
  float*          vq     = (float*)(ws + 35651584);
  float*          uq     = (float*)(ws + 35657728);
  float*          vf     = (float*)(ws + 35663872);
  float*          uf     = (float*)(ws + 35672064);
  float2*         stats1 = (float2*)(ws + 35680256);
  float*          stats2 = (float*)(ws + 35713024);

  // 1. prep
  prep<<<4156, 256, 0, stream>>>(w_qkv, w_out, w_ff1, w_ff2,
                                 ln1_g, ln1_b, ln2_g, ln2_b, b_qkv, b_ff1, x,
                                 wqkvT, woutT, wff1T, wff2T,
                                 vq, uq, vf, uf, x_bf, stats1, stats2);

  // 2. LN1+QKV fused -> bf16   (128x128 tiles, 384 blocks, 3/CU)
  gemm128<4><<<(1536/128)*(NROWS/128), 256, 0, stream>>>(
      x_bf, wqkvT, vq, uq, (const float*)stats1, qkv_bf, NROWS, 1536, DMODEL, DMODEL);

  // 3. sparse geometric attention -> bf16 (XCD-swizzled)
  attn_kernel<<<NROWS, 64, 0, stream>>>(qkv_bf, coords_pos, coords_level, at_bf);

  // 4. out-proj + residual(x fp32) -> x1 bf16, atomic row stats
  //    (BM=32: 1024 blocks, 4/CU)
  gemm_bf16<5, 32><<<(DMODEL/64)*(NROWS/32), 256, 0, stream>>>(
      at_bf, woutT, b_out, x, nullptr, stats2, x1_bf, NROWS, DMODEL, DMODEL, DMODEL);

  // 5. LN2+FF1+GELU fused -> bf16   (128x128 tiles, 512 blocks, 3/CU)
  gemm128<6><<<(DFF/128)*(NROWS/128), 256, 0, stream>>>(
      x1_bf, wff1T, vf, uf, stats2, h_bf, NROWS, DFF, DMODEL, DMODEL);

  // 6. FF2 + residual(x1 bf16) -> d_out fp32   (BM=32: 1024 blocks, 4/CU)
  gemm_bf16<7, 32><<<(DMODEL/64)*(NROWS/32), 256, 0, stream>>>(
      h_bf, wff2T, b_ff2, nullptr, x1_bf, nullptr, out, NROWS, DMODEL, DFF, DFF);
}